// Round 1
// baseline (517.523 us; speedup 1.0000x reference)
//
#include <hip/hip_runtime.h>

#define BN_EPS 1e-5f

// ---------------- CSR construction ----------------

__global__ void k_hist(const int* __restrict__ ei, int E, int* __restrict__ cnt) {
    int e = blockIdx.x * blockDim.x + threadIdx.x;
    if (e < E) atomicAdd(&cnt[ei[E + e]], 1);
}

__global__ void k_block_sum(const int* __restrict__ cnt, int N, int* __restrict__ bsum) {
    __shared__ int s[256];
    int i = blockIdx.x * 256 + threadIdx.x;
    int v = (i < N) ? cnt[i] : 0;
    s[threadIdx.x] = v;
    __syncthreads();
    for (int off = 128; off > 0; off >>= 1) {
        if (threadIdx.x < off) s[threadIdx.x] += s[threadIdx.x + off];
        __syncthreads();
    }
    if (threadIdx.x == 0) bsum[blockIdx.x] = s[0];
}

// single block of 1024 threads: exclusive scan of block sums (nB <= 1024)
__global__ void k_scan_bsums(const int* __restrict__ bsum, int nB, int* __restrict__ bscan) {
    __shared__ int s[1024];
    int t = threadIdx.x;
    int v = (t < nB) ? bsum[t] : 0;
    s[t] = v;
    __syncthreads();
    for (int off = 1; off < 1024; off <<= 1) {
        int add = (t >= off) ? s[t - off] : 0;
        __syncthreads();
        s[t] += add;
        __syncthreads();
    }
    if (t < nB) bscan[t] = s[t] - v;  // exclusive
}

__global__ void k_scan_rowptr(const int* __restrict__ cnt, const int* __restrict__ bscan,
                              int N, int E, int* __restrict__ rowptr,
                              float* __restrict__ dinv) {
    __shared__ int s[256];
    int t = threadIdx.x;
    int i = blockIdx.x * 256 + t;
    int v = (i < N) ? cnt[i] : 0;
    s[t] = v;
    __syncthreads();
    for (int off = 1; off < 256; off <<= 1) {
        int add = (t >= off) ? s[t - off] : 0;
        __syncthreads();
        s[t] += add;
        __syncthreads();
    }
    if (i < N) {
        rowptr[i] = bscan[blockIdx.x] + s[t] - v;         // exclusive scan
        dinv[i] = rsqrtf((float)(v + 1));                  // deg incl. self-loop >= 1
    }
    if (i == 0) rowptr[N] = E;
}

__global__ void k_fill(const int* __restrict__ ei, int E, const int* __restrict__ rowptr,
                       int* __restrict__ fillc, int* __restrict__ col) {
    int e = blockIdx.x * blockDim.x + threadIdx.x;
    if (e < E) {
        int s = ei[e];          // src
        int d = ei[E + e];      // dst
        int pos = rowptr[d] + atomicAdd(&fillc[d], 1);
        col[pos] = s;
    }
}

// ---------------- aggregation: aggx[i] = dinv[i]^2 * x[i] + sum_j dinv[i]*dinv[j]*x[j] ----------------

__global__ void __launch_bounds__(128) k_agg(const float* __restrict__ x,
                                             const int* __restrict__ rowptr,
                                             const int* __restrict__ col,
                                             const float* __restrict__ dinv,
                                             float* __restrict__ aggx) {
    int i = blockIdx.x;
    int d = threadIdx.x;
    float di = dinv[i];
    float acc = x[(size_t)i * 128 + d] * (di * di);
    int e0 = rowptr[i], e1 = rowptr[i + 1];
    for (int e = e0; e < e1; ++e) {
        int s = col[e];
        float w = dinv[s] * di;
        acc += x[(size_t)s * 128 + d] * w;
    }
    aggx[(size_t)i * 128 + d] = acc;
}

// ---------------- GEMM: out[r][j] = sum_k A[r][k] * W[j][k] + b[j] ----------------
// tile: 64 rows x 128 cols, K chunked by 32 so LDS stays under 64 KB.

__global__ void __launch_bounds__(256) k_gemm(const float* __restrict__ A,
                                              const float* __restrict__ W,
                                              const float* __restrict__ bias,
                                              int N, float* __restrict__ out) {
    __shared__ float xs[64 * 132];   // x tile, padded stride 132
    __shared__ float wt[32 * 132];   // W^T chunk [k_local][j]

    int t = threadIdx.x;
    int r0 = blockIdx.x * 64;

    // stage x tile (float4)
    #pragma unroll
    for (int it = 0; it < 8; ++it) {
        int idx = t + it * 256;          // 0..2047
        int row = idx >> 5, c4 = idx & 31;
        int r = r0 + row;
        float4 v = make_float4(0.f, 0.f, 0.f, 0.f);
        if (r < N) v = *(const float4*)&A[(size_t)r * 128 + c4 * 4];
        *(float4*)&xs[row * 132 + c4 * 4] = v;
    }

    int cg = t & 31;      // col group: cols 4cg..4cg+3
    int rg = t >> 5;      // row group: rows rg*8..rg*8+7
    float acc[8][4];
    #pragma unroll
    for (int i = 0; i < 8; ++i)
        #pragma unroll
        for (int c = 0; c < 4; ++c) acc[i][c] = 0.f;

    for (int kc = 0; kc < 4; ++kc) {
        __syncthreads();   // xs staged / previous chunk reads done
        // stage W^T chunk: wt[kl][j] = W[j][kc*32+kl]
        #pragma unroll
        for (int it = 0; it < 16; ++it) {
            int idx = t + it * 256;      // 0..4095
            int j = idx >> 5, kl = idx & 31;
            wt[kl * 132 + j] = W[j * 128 + kc * 32 + kl];
        }
        __syncthreads();
        #pragma unroll
        for (int kl = 0; kl < 32; ++kl) {
            int k = kc * 32 + kl;
            float4 wv = *(const float4*)&wt[kl * 132 + cg * 4];
            #pragma unroll
            for (int i = 0; i < 8; ++i) {
                float a = xs[(rg * 8 + i) * 132 + k];
                acc[i][0] += a * wv.x;
                acc[i][1] += a * wv.y;
                acc[i][2] += a * wv.z;
                acc[i][3] += a * wv.w;
            }
        }
    }

    float4 bv = *(const float4*)&bias[cg * 4];
    #pragma unroll
    for (int i = 0; i < 8; ++i) {
        int r = r0 + rg * 8 + i;
        if (r < N) {
            float4 o;
            o.x = acc[i][0] + bv.x;
            o.y = acc[i][1] + bv.y;
            o.z = acc[i][2] + bv.z;
            o.w = acc[i][3] + bv.w;
            *(float4*)&out[(size_t)r * 128 + cg * 4] = o;
        }
    }
}

// ---------------- BN stats ----------------

__global__ void __launch_bounds__(128) k_stats(const float* __restrict__ out, int N,
                                               float* __restrict__ sums) {
    int t = threadIdx.x;             // column
    int r0 = blockIdx.x * 256;
    int rend = r0 + 256;
    if (rend > N) rend = N;
    float s = 0.f, sq = 0.f;
    for (int r = r0; r < rend; ++r) {
        float v = out[(size_t)r * 128 + t];
        s += v;
        sq += v * v;
    }
    atomicAdd(&sums[t], s);
    atomicAdd(&sums[128 + t], sq);
}

__global__ void k_bnparams(const float* __restrict__ sums, const float* __restrict__ gamma,
                           const float* __restrict__ beta, float invN,
                           float* __restrict__ ss) {
    int t = threadIdx.x;  // 128
    float mean = sums[t] * invN;
    float var = sums[128 + t] * invN - mean * mean;
    float sc = gamma[t] * rsqrtf(var + BN_EPS);
    ss[t] = sc;
    ss[128 + t] = beta[t] - mean * sc;
}

// ---------------- fused BN-apply + ReLU + residual ----------------

__global__ void k_final(float* __restrict__ out, const float* __restrict__ x,
                        const float* __restrict__ ss, int total4) {
    int idx = blockIdx.x * blockDim.x + threadIdx.x;
    int stride = gridDim.x * blockDim.x;
    for (; idx < total4; idx += stride) {
        int c4 = idx & 31;  // float4-column within 128
        float4 v = ((const float4*)out)[idx];
        float4 xv = ((const float4*)x)[idx];
        float4 sc = *(const float4*)&ss[c4 * 4];
        float4 sh = *(const float4*)&ss[128 + c4 * 4];
        float4 o;
        o.x = fmaxf(v.x * sc.x + sh.x, 0.f) + xv.x;
        o.y = fmaxf(v.y * sc.y + sh.y, 0.f) + xv.y;
        o.z = fmaxf(v.z * sc.z + sh.z, 0.f) + xv.z;
        o.w = fmaxf(v.w * sc.w + sh.w, 0.f) + xv.w;
        ((float4*)out)[idx] = o;
    }
}

// ---------------- launcher ----------------

extern "C" void kernel_launch(void* const* d_in, const int* in_sizes, int n_in,
                              void* d_out, int out_size, void* d_ws, size_t ws_size,
                              hipStream_t stream) {
    const float* x     = (const float*)d_in[0];
    const int*   ei    = (const int*)d_in[1];
    const float* W     = (const float*)d_in[2];
    const float* bias  = (const float*)d_in[3];
    const float* gamma = (const float*)d_in[4];
    const float* beta  = (const float*)d_in[5];
    float* out = (float*)d_out;

    const int D = 128;
    int N = in_sizes[0] / D;
    int E = in_sizes[1] / 2;

    char* ws = (char*)d_ws;
    size_t off = 0;
    auto alloc = [&](size_t bytes) -> void* {
        void* p = ws + off;
        off += (bytes + 255) & ~(size_t)255;
        return p;
    };
    float* aggx  = (float*)alloc((size_t)N * D * sizeof(float));
    int* cnt     = (int*)alloc((size_t)N * sizeof(int));
    int* rowptr  = (int*)alloc((size_t)(N + 1) * sizeof(int));
    int* fillc   = (int*)alloc((size_t)N * sizeof(int));
    int* col     = (int*)alloc((size_t)E * sizeof(int));
    float* dinv  = (float*)alloc((size_t)N * sizeof(float));
    int nB = (N + 255) / 256;
    int* bsum    = (int*)alloc((size_t)nB * sizeof(int));
    int* bscan   = (int*)alloc((size_t)nB * sizeof(int));
    float* sums  = (float*)alloc(256 * sizeof(float));
    float* ss    = (float*)alloc(256 * sizeof(float));

    hipMemsetAsync(cnt, 0, (size_t)N * sizeof(int), stream);
    hipMemsetAsync(fillc, 0, (size_t)N * sizeof(int), stream);
    hipMemsetAsync(sums, 0, 256 * sizeof(float), stream);

    k_hist<<<(E + 255) / 256, 256, 0, stream>>>(ei, E, cnt);
    k_block_sum<<<nB, 256, 0, stream>>>(cnt, N, bsum);
    k_scan_bsums<<<1, 1024, 0, stream>>>(bsum, nB, bscan);
    k_scan_rowptr<<<nB, 256, 0, stream>>>(cnt, bscan, N, E, rowptr, dinv);
    k_fill<<<(E + 255) / 256, 256, 0, stream>>>(ei, E, rowptr, fillc, col);
    k_agg<<<N, 128, 0, stream>>>(x, rowptr, col, dinv, aggx);
    k_gemm<<<(N + 63) / 64, 256, 0, stream>>>(aggx, W, bias, N, out);
    k_stats<<<(N + 255) / 256, 128, 0, stream>>>(out, N, sums);
    k_bnparams<<<1, 128, 0, stream>>>(sums, gamma, beta, 1.0f / (float)N, ss);
    k_final<<<2048, 256, 0, stream>>>(out, x, ss, N * D / 4);
}

// Round 2
// 376.326 us; speedup vs baseline: 1.3752x; 1.3752x over previous
//
#include <hip/hip_runtime.h>

#define BN_EPS 1e-5f

typedef unsigned int uint32;
typedef __attribute__((ext_vector_type(8))) short bf16x8;
typedef __attribute__((ext_vector_type(4))) float f32x4;

__device__ __forceinline__ float bf_lo(uint32 v) {
    union { uint32 u; float f; } c; c.u = v << 16; return c.f;
}
__device__ __forceinline__ float bf_hi(uint32 v) {
    union { uint32 u; float f; } c; c.u = v & 0xffff0000u; return c.f;
}
__device__ __forceinline__ uint32 f2bf(float f) {  // RNE, result in low 16 bits
    union { float f; uint32 u; } c; c.f = f;
    uint32 u = c.u;
    u += 0x7fffu + ((u >> 16) & 1u);
    return u >> 16;
}

// ---------------- fp32 -> bf16 conversion (x and W) ----------------

__global__ void k_convert(const float4* __restrict__ in, uint2* __restrict__ outb, int total4) {
    int i = blockIdx.x * blockDim.x + threadIdx.x;
    int stride = gridDim.x * blockDim.x;
    for (; i < total4; i += stride) {
        float4 v = in[i];
        uint2 o;
        o.x = f2bf(v.x) | (f2bf(v.y) << 16);
        o.y = f2bf(v.z) | (f2bf(v.w) << 16);
        outb[i] = o;
    }
}

// ---------------- CSR construction ----------------

__global__ void k_hist(const int* __restrict__ ei, int E, int* __restrict__ cnt) {
    int e = blockIdx.x * blockDim.x + threadIdx.x;
    if (e < E) atomicAdd(&cnt[ei[E + e]], 1);
}

__global__ void k_block_sum(const int* __restrict__ cnt, int N, int* __restrict__ bsum) {
    __shared__ int s[256];
    int i = blockIdx.x * 256 + threadIdx.x;
    int v = (i < N) ? cnt[i] : 0;
    s[threadIdx.x] = v;
    __syncthreads();
    for (int off = 128; off > 0; off >>= 1) {
        if (threadIdx.x < off) s[threadIdx.x] += s[threadIdx.x + off];
        __syncthreads();
    }
    if (threadIdx.x == 0) bsum[blockIdx.x] = s[0];
}

__global__ void k_scan_bsums(const int* __restrict__ bsum, int nB, int* __restrict__ bscan) {
    __shared__ int s[1024];
    int t = threadIdx.x;
    int v = (t < nB) ? bsum[t] : 0;
    s[t] = v;
    __syncthreads();
    for (int off = 1; off < 1024; off <<= 1) {
        int add = (t >= off) ? s[t - off] : 0;
        __syncthreads();
        s[t] += add;
        __syncthreads();
    }
    if (t < nB) bscan[t] = s[t] - v;  // exclusive
}

__global__ void k_scan_rowptr(const int* __restrict__ cnt, const int* __restrict__ bscan,
                              int N, int E, int* __restrict__ rowptr,
                              float* __restrict__ dinv) {
    __shared__ int s[256];
    int t = threadIdx.x;
    int i = blockIdx.x * 256 + t;
    int v = (i < N) ? cnt[i] : 0;
    s[t] = v;
    __syncthreads();
    for (int off = 1; off < 256; off <<= 1) {
        int add = (t >= off) ? s[t - off] : 0;
        __syncthreads();
        s[t] += add;
        __syncthreads();
    }
    if (i < N) {
        rowptr[i] = bscan[blockIdx.x] + s[t] - v;  // exclusive scan
        dinv[i] = rsqrtf((float)(v + 1));           // deg incl. self-loop
    }
    if (i == 0) rowptr[N] = E;
}

__global__ void k_fill(const int* __restrict__ ei, int E, const int* __restrict__ rowptr,
                       int* __restrict__ fillc, int* __restrict__ col) {
    int e = blockIdx.x * blockDim.x + threadIdx.x;
    if (e < E) {
        int s = ei[e];
        int d = ei[E + e];
        int pos = rowptr[d] + atomicAdd(&fillc[d], 1);
        col[pos] = s;
    }
}

// ---------------- aggregation: wave-per-node, bf16 rows ----------------
// aggx[i] = di^2*x[i] + sum_j di*dinv[j]*x[j]  = di*(di*x[i] + sum dinv[j]*x[j])

__global__ void __launch_bounds__(256) k_agg(const uint32* __restrict__ xb,
                                             const int* __restrict__ rowptr,
                                             const int* __restrict__ col,
                                             const float* __restrict__ dinv,
                                             uint32* __restrict__ aggb, int N) {
    int wid = blockIdx.x * 4 + (threadIdx.x >> 6);
    wid = __builtin_amdgcn_readfirstlane(wid);
    if (wid >= N) return;
    int lane = threadIdx.x & 63;

    float di = dinv[wid];
    uint32 sv = xb[(size_t)wid * 64 + lane];
    float acc0 = di * bf_lo(sv);
    float acc1 = di * bf_hi(sv);

    int e0 = rowptr[wid], e1 = rowptr[wid + 1];
    int e = e0;
    for (; e + 4 <= e1; e += 4) {
        int s0 = col[e], s1 = col[e + 1], s2 = col[e + 2], s3 = col[e + 3];
        float w0 = dinv[s0], w1 = dinv[s1], w2 = dinv[s2], w3 = dinv[s3];
        uint32 v0 = xb[(size_t)s0 * 64 + lane];
        uint32 v1 = xb[(size_t)s1 * 64 + lane];
        uint32 v2 = xb[(size_t)s2 * 64 + lane];
        uint32 v3 = xb[(size_t)s3 * 64 + lane];
        acc0 += w0 * bf_lo(v0); acc1 += w0 * bf_hi(v0);
        acc0 += w1 * bf_lo(v1); acc1 += w1 * bf_hi(v1);
        acc0 += w2 * bf_lo(v2); acc1 += w2 * bf_hi(v2);
        acc0 += w3 * bf_lo(v3); acc1 += w3 * bf_hi(v3);
    }
    for (; e < e1; ++e) {
        int s = col[e];
        float w = dinv[s];
        uint32 v = xb[(size_t)s * 64 + lane];
        acc0 += w * bf_lo(v); acc1 += w * bf_hi(v);
    }
    acc0 *= di; acc1 *= di;
    aggb[(size_t)wid * 64 + lane] = f2bf(acc0) | (f2bf(acc1) << 16);
}

// ---------------- MFMA GEMM: out[r][j] = sum_k A[r][k]*W[j][k] + b[j], fused BN stats ---------
// block = 256 threads = 4 waves; wave handles 16 rows x 128 cols; K=128 in 4 chunks of 32.
// mfma_f32_16x16x32_bf16: A lane: row=lane&15, k=(lane>>4)*8+i ; B lane: col=lane&15, same k.
// C/D: col=lane&15, row=(lane>>4)*4+reg.

__global__ void __launch_bounds__(256) k_gemm(const short* __restrict__ Ab,
                                              const short* __restrict__ Wb,
                                              const float* __restrict__ bias,
                                              int N, float* __restrict__ out,
                                              float* __restrict__ sums) {
    __shared__ float lsum[256];  // [c]=sum, [128+c]=sumsq
    int t = threadIdx.x;
    if (t < 128) { lsum[t] = 0.f; lsum[t + 128] = 0.f; }
    __syncthreads();

    int wave = t >> 6, lane = t & 63;
    int r0 = blockIdx.x * 64 + wave * 16;
    int lrow = lane & 15;
    int lk = (lane >> 4) * 8;

    f32x4 acc[8];
    #pragma unroll
    for (int ct = 0; ct < 8; ++ct) acc[ct] = (f32x4){0.f, 0.f, 0.f, 0.f};

    int arow = r0 + lrow;
    bool avalid = arow < N;
    #pragma unroll
    for (int kc = 0; kc < 4; ++kc) {
        bf16x8 a;
        if (avalid) a = *(const bf16x8*)&Ab[(size_t)arow * 128 + kc * 32 + lk];
        else        a = (bf16x8){0, 0, 0, 0, 0, 0, 0, 0};
        #pragma unroll
        for (int ct = 0; ct < 8; ++ct) {
            bf16x8 b = *(const bf16x8*)&Wb[(ct * 16 + lrow) * 128 + kc * 32 + lk];
            acc[ct] = __builtin_amdgcn_mfma_f32_16x16x32_bf16(a, b, acc[ct], 0, 0, 0);
        }
    }

    int orow0 = r0 + (lane >> 4) * 4;
    #pragma unroll
    for (int ct = 0; ct < 8; ++ct) {
        int ocol = ct * 16 + lrow;
        float bv = bias[ocol];
        float s = 0.f, sq = 0.f;
        #pragma unroll
        for (int rr = 0; rr < 4; ++rr) {
            int r = orow0 + rr;
            if (r < N) {
                float o = acc[ct][rr] + bv;
                out[(size_t)r * 128 + ocol] = o;
                s += o; sq += o * o;
            }
        }
        atomicAdd(&lsum[ocol], s);
        atomicAdd(&lsum[128 + ocol], sq);
    }
    __syncthreads();
    if (t < 128) {
        atomicAdd(&sums[t], lsum[t]);
        atomicAdd(&sums[128 + t], lsum[t + 128]);
    }
}

// ---------------- BN params ----------------

__global__ void k_bnparams(const float* __restrict__ sums, const float* __restrict__ gamma,
                           const float* __restrict__ beta, float invN,
                           float* __restrict__ ss) {
    int t = threadIdx.x;  // 128
    float mean = sums[t] * invN;
    float var = sums[128 + t] * invN - mean * mean;
    float sc = gamma[t] * rsqrtf(var + BN_EPS);
    ss[t] = sc;
    ss[128 + t] = beta[t] - mean * sc;
}

// ---------------- fused BN-apply + ReLU + residual ----------------

__global__ void k_final(float* __restrict__ out, const float* __restrict__ x,
                        const float* __restrict__ ss, int total4) {
    int idx = blockIdx.x * blockDim.x + threadIdx.x;
    int stride = gridDim.x * blockDim.x;
    for (; idx < total4; idx += stride) {
        int c4 = idx & 31;
        float4 v = ((const float4*)out)[idx];
        float4 xv = ((const float4*)x)[idx];
        float4 sc = *(const float4*)&ss[c4 * 4];
        float4 sh = *(const float4*)&ss[128 + c4 * 4];
        float4 o;
        o.x = fmaxf(v.x * sc.x + sh.x, 0.f) + xv.x;
        o.y = fmaxf(v.y * sc.y + sh.y, 0.f) + xv.y;
        o.z = fmaxf(v.z * sc.z + sh.z, 0.f) + xv.z;
        o.w = fmaxf(v.w * sc.w + sh.w, 0.f) + xv.w;
        ((float4*)out)[idx] = o;
    }
}

// ---------------- launcher ----------------

extern "C" void kernel_launch(void* const* d_in, const int* in_sizes, int n_in,
                              void* d_out, int out_size, void* d_ws, size_t ws_size,
                              hipStream_t stream) {
    const float* x     = (const float*)d_in[0];
    const int*   ei    = (const int*)d_in[1];
    const float* W     = (const float*)d_in[2];
    const float* bias  = (const float*)d_in[3];
    const float* gamma = (const float*)d_in[4];
    const float* beta  = (const float*)d_in[5];
    float* out = (float*)d_out;

    const int D = 128;
    int N = in_sizes[0] / D;
    int E = in_sizes[1] / 2;

    char* ws = (char*)d_ws;
    size_t off = 0;
    auto alloc = [&](size_t bytes) -> void* {
        void* p = ws + off;
        off += (bytes + 255) & ~(size_t)255;
        return p;
    };
    uint32* xb   = (uint32*)alloc((size_t)N * 64 * sizeof(uint32));   // x in bf16
    uint32* aggb = (uint32*)alloc((size_t)N * 64 * sizeof(uint32));   // aggx in bf16
    short*  Wb   = (short*)alloc((size_t)D * D * sizeof(short));      // W in bf16
    int* cnt     = (int*)alloc((size_t)N * sizeof(int));
    int* rowptr  = (int*)alloc((size_t)(N + 1) * sizeof(int));
    int* fillc   = (int*)alloc((size_t)N * sizeof(int));
    int* col     = (int*)alloc((size_t)E * sizeof(int));
    float* dinv  = (float*)alloc((size_t)N * sizeof(float));
    int nB = (N + 255) / 256;
    int* bsum    = (int*)alloc((size_t)nB * sizeof(int));
    int* bscan   = (int*)alloc((size_t)nB * sizeof(int));
    float* sums  = (float*)alloc(256 * sizeof(float));
    float* ss    = (float*)alloc(256 * sizeof(float));

    hipMemsetAsync(cnt, 0, (size_t)N * sizeof(int), stream);
    hipMemsetAsync(fillc, 0, (size_t)N * sizeof(int), stream);
    hipMemsetAsync(sums, 0, 256 * sizeof(float), stream);

    k_convert<<<2048, 256, 0, stream>>>((const float4*)x, (uint2*)xb, N * D / 4);
    k_convert<<<16, 256, 0, stream>>>((const float4*)W, (uint2*)Wb, D * D / 4);
    k_hist<<<(E + 255) / 256, 256, 0, stream>>>(ei, E, cnt);
    k_block_sum<<<nB, 256, 0, stream>>>(cnt, N, bsum);
    k_scan_bsums<<<1, 1024, 0, stream>>>(bsum, nB, bscan);
    k_scan_rowptr<<<nB, 256, 0, stream>>>(cnt, bscan, N, E, rowptr, dinv);
    k_fill<<<(E + 255) / 256, 256, 0, stream>>>(ei, E, rowptr, fillc, col);
    k_agg<<<(N + 3) / 4, 256, 0, stream>>>(xb, rowptr, col, dinv, aggb, N);
    k_gemm<<<(N + 63) / 64, 256, 0, stream>>>((const short*)aggb, Wb, bias, N, out, sums);
    k_bnparams<<<1, 128, 0, stream>>>(sums, gamma, beta, 1.0f / (float)N, ss);
    k_final<<<2048, 256, 0, stream>>>(out, x, ss, N * D / 4);
}

// Round 3
// 318.283 us; speedup vs baseline: 1.6260x; 1.1824x over previous
//
#include <hip/hip_runtime.h>

#define BN_EPS 1e-5f

typedef unsigned int uint32;
typedef __attribute__((ext_vector_type(8))) short bf16x8;
typedef __attribute__((ext_vector_type(4))) float f32x4;

__device__ __forceinline__ float bf_lo(uint32 v) {
    union { uint32 u; float f; } c; c.u = v << 16; return c.f;
}
__device__ __forceinline__ float bf_hi(uint32 v) {
    union { uint32 u; float f; } c; c.u = v & 0xffff0000u; return c.f;
}
__device__ __forceinline__ uint32 f2bf(float f) {  // RNE, low 16 bits
    union { float f; uint32 u; } c; c.f = f;
    uint32 u = c.u;
    u += 0x7fffu + ((u >> 16) & 1u);
    return u >> 16;
}

// ---------------- fp32 -> bf16 ----------------

__global__ void k_convert(const float4* __restrict__ in, uint2* __restrict__ outb, int total4) {
    int i = blockIdx.x * blockDim.x + threadIdx.x;
    int stride = gridDim.x * blockDim.x;
    for (; i < total4; i += stride) {
        float4 v = in[i];
        uint2 o;
        o.x = f2bf(v.x) | (f2bf(v.y) << 16);
        o.y = f2bf(v.z) | (f2bf(v.w) << 16);
        outb[i] = o;
    }
}

// ---------------- bucket partition (counting sort by dst>>SH) ----------------

__global__ void __launch_bounds__(256) k_bhist(const int* __restrict__ dst, int E, int NB, int SH,
                                               int* __restrict__ bcnt) {
    __shared__ int h[1024];
    for (int i = threadIdx.x; i < NB; i += 256) h[i] = 0;
    __syncthreads();
    int idx = blockIdx.x * 256 + threadIdx.x;
    int stride = gridDim.x * 256;
    for (int e = idx; e < E; e += stride) atomicAdd(&h[dst[e] >> SH], 1);
    __syncthreads();
    for (int i = threadIdx.x; i < NB; i += 256)
        if (h[i]) atomicAdd(&bcnt[i], h[i]);
}

// exclusive scan of up to 1024 values (single block of 1024 threads)
__global__ void k_scan1024(const int* __restrict__ in, int n, int* __restrict__ outExcl) {
    __shared__ int s[1024];
    int t = threadIdx.x;
    int v = (t < n) ? in[t] : 0;
    s[t] = v;
    __syncthreads();
    for (int off = 1; off < 1024; off <<= 1) {
        int add = (t >= off) ? s[t - off] : 0;
        __syncthreads();
        s[t] += add;
        __syncthreads();
    }
    if (t < n) outExcl[t] = s[t] - v;
}

__global__ void __launch_bounds__(256) k_bscatter(const int* __restrict__ ei, int E, int NB, int SH,
                                                  const int* __restrict__ bbase,
                                                  int* __restrict__ bfill,
                                                  int2* __restrict__ bpairs) {
    __shared__ int h[1024];
    int nBlk = gridDim.x;
    int c0 = (int)((long long)blockIdx.x * E / nBlk);
    int c1 = (int)((long long)(blockIdx.x + 1) * E / nBlk);
    for (int i = threadIdx.x; i < NB; i += 256) h[i] = 0;
    __syncthreads();
    // sweep 1: count
    for (int e = c0 + threadIdx.x; e < c1; e += 256)
        atomicAdd(&h[ei[E + e] >> SH], 1);
    __syncthreads();
    // reserve: h[i] becomes this block's absolute write cursor for bucket i
    for (int i = threadIdx.x; i < NB; i += 256) {
        int c = h[i];
        if (c > 0) h[i] = bbase[i] + atomicAdd(&bfill[i], c);
    }
    __syncthreads();
    // sweep 2: rank + write
    for (int e = c0 + threadIdx.x; e < c1; e += 256) {
        int s = ei[e];
        int d = ei[E + e];
        int pos = atomicAdd(&h[d >> SH], 1);
        bpairs[pos] = make_int2(s, d);
    }
}

// ---------------- degree histogram over bucket-grouped pairs ----------------

__global__ void __launch_bounds__(256) k_hist2(const int2* __restrict__ bpairs, int E,
                                               int* __restrict__ cnt) {
    int nBlk = gridDim.x;
    int c0 = (int)((long long)blockIdx.x * E / nBlk);
    int c1 = (int)((long long)(blockIdx.x + 1) * E / nBlk);
    for (int e = c0 + threadIdx.x; e < c1; e += 256)
        atomicAdd(&cnt[bpairs[e].y], 1);
}

__global__ void k_block_sum(const int* __restrict__ cnt, int N, int* __restrict__ bsum) {
    __shared__ int s[256];
    int i = blockIdx.x * 256 + threadIdx.x;
    int v = (i < N) ? cnt[i] : 0;
    s[threadIdx.x] = v;
    __syncthreads();
    for (int off = 128; off > 0; off >>= 1) {
        if (threadIdx.x < off) s[threadIdx.x] += s[threadIdx.x + off];
        __syncthreads();
    }
    if (threadIdx.x == 0) bsum[blockIdx.x] = s[0];
}

__global__ void k_scan_rowptr(const int* __restrict__ cnt, const int* __restrict__ bscan,
                              int N, int E, int* __restrict__ rowptr,
                              float* __restrict__ dinv) {
    __shared__ int s[256];
    int t = threadIdx.x;
    int i = blockIdx.x * 256 + t;
    int v = (i < N) ? cnt[i] : 0;
    s[t] = v;
    __syncthreads();
    for (int off = 1; off < 256; off <<= 1) {
        int add = (t >= off) ? s[t - off] : 0;
        __syncthreads();
        s[t] += add;
        __syncthreads();
    }
    if (i < N) {
        rowptr[i] = bscan[blockIdx.x] + s[t] - v;  // exclusive
        dinv[i] = rsqrtf((float)(v + 1));           // deg incl. self-loop
    }
    if (i == 0) rowptr[N] = E;
}

// ---------------- CSR fill from bucket-grouped pairs (localized scatter) ----------------

__global__ void __launch_bounds__(256) k_fill2(const int2* __restrict__ bpairs, int E,
                                               const int* __restrict__ rowptr,
                                               int* __restrict__ fillc, int* __restrict__ col) {
    int nBlk = gridDim.x;
    int c0 = (int)((long long)blockIdx.x * E / nBlk);
    int c1 = (int)((long long)(blockIdx.x + 1) * E / nBlk);
    for (int e = c0 + threadIdx.x; e < c1; e += 256) {
        int2 p = bpairs[e];
        int pos = rowptr[p.y] + atomicAdd(&fillc[p.y], 1);
        col[pos] = p.x;
    }
}

// ---------------- aggregation: wave-per-node, bf16 rows ----------------
// aggx[i] = di*(di*x[i] + sum_j dinv[j]*x[j])

__global__ void __launch_bounds__(256) k_agg(const uint32* __restrict__ xb,
                                             const int* __restrict__ rowptr,
                                             const int* __restrict__ col,
                                             const float* __restrict__ dinv,
                                             uint32* __restrict__ aggb, int N) {
    int wid = blockIdx.x * 4 + (threadIdx.x >> 6);
    wid = __builtin_amdgcn_readfirstlane(wid);
    if (wid >= N) return;
    int lane = threadIdx.x & 63;

    float di = dinv[wid];
    uint32 sv = xb[(size_t)wid * 64 + lane];
    float acc0 = di * bf_lo(sv);
    float acc1 = di * bf_hi(sv);

    int e0 = rowptr[wid], e1 = rowptr[wid + 1];
    int e = e0;
    for (; e + 4 <= e1; e += 4) {
        int s0 = col[e], s1 = col[e + 1], s2 = col[e + 2], s3 = col[e + 3];
        float w0 = dinv[s0], w1 = dinv[s1], w2 = dinv[s2], w3 = dinv[s3];
        uint32 v0 = xb[(size_t)s0 * 64 + lane];
        uint32 v1 = xb[(size_t)s1 * 64 + lane];
        uint32 v2 = xb[(size_t)s2 * 64 + lane];
        uint32 v3 = xb[(size_t)s3 * 64 + lane];
        acc0 += w0 * bf_lo(v0); acc1 += w0 * bf_hi(v0);
        acc0 += w1 * bf_lo(v1); acc1 += w1 * bf_hi(v1);
        acc0 += w2 * bf_lo(v2); acc1 += w2 * bf_hi(v2);
        acc0 += w3 * bf_lo(v3); acc1 += w3 * bf_hi(v3);
    }
    for (; e < e1; ++e) {
        int s = col[e];
        float w = dinv[s];
        uint32 v = xb[(size_t)s * 64 + lane];
        acc0 += w * bf_lo(v); acc1 += w * bf_hi(v);
    }
    acc0 *= di; acc1 *= di;
    aggb[(size_t)wid * 64 + lane] = f2bf(acc0) | (f2bf(acc1) << 16);
}

// ---------------- MFMA GEMM pass 1: BN column sums only (no store) ----------------
// block = 256 = 4 waves; wave: 16 rows x 128 cols; K=128 in 4 chunks.
// C/D layout: col=lane&15, row=(lane>>4)*4+reg.

__global__ void __launch_bounds__(256) k_gemm_stats(const short* __restrict__ Ab,
                                                    const short* __restrict__ Wb,
                                                    const float* __restrict__ bias,
                                                    int N, float* __restrict__ sums) {
    __shared__ float lsum[256];
    int t = threadIdx.x;
    if (t < 128) { lsum[t] = 0.f; lsum[t + 128] = 0.f; }
    __syncthreads();

    int wave = t >> 6, lane = t & 63;
    int r0 = blockIdx.x * 64 + wave * 16;
    int lrow = lane & 15;
    int lk = (lane >> 4) * 8;

    f32x4 acc[8];
    #pragma unroll
    for (int ct = 0; ct < 8; ++ct) acc[ct] = (f32x4){0.f, 0.f, 0.f, 0.f};

    int arow = r0 + lrow;
    bool avalid = arow < N;
    #pragma unroll
    for (int kc = 0; kc < 4; ++kc) {
        bf16x8 a;
        if (avalid) a = *(const bf16x8*)&Ab[(size_t)arow * 128 + kc * 32 + lk];
        else        a = (bf16x8){0, 0, 0, 0, 0, 0, 0, 0};
        #pragma unroll
        for (int ct = 0; ct < 8; ++ct) {
            bf16x8 b = *(const bf16x8*)&Wb[(ct * 16 + lrow) * 128 + kc * 32 + lk];
            acc[ct] = __builtin_amdgcn_mfma_f32_16x16x32_bf16(a, b, acc[ct], 0, 0, 0);
        }
    }

    int orow0 = r0 + (lane >> 4) * 4;
    #pragma unroll
    for (int ct = 0; ct < 8; ++ct) {
        int ocol = ct * 16 + lrow;
        float bv = bias[ocol];
        float s = 0.f, sq = 0.f;
        #pragma unroll
        for (int rr = 0; rr < 4; ++rr) {
            int r = orow0 + rr;
            if (r < N) {
                float o = acc[ct][rr] + bv;
                s += o; sq += o * o;
            }
        }
        atomicAdd(&lsum[ocol], s);
        atomicAdd(&lsum[128 + ocol], sq);
    }
    __syncthreads();
    if (t < 128) {
        atomicAdd(&sums[t], lsum[t]);
        atomicAdd(&sums[128 + t], lsum[t + 128]);
    }
}

// ---------------- BN params ----------------

__global__ void k_bnparams(const float* __restrict__ sums, const float* __restrict__ gamma,
                           const float* __restrict__ beta, float invN,
                           float* __restrict__ ss) {
    int t = threadIdx.x;  // 128
    float mean = sums[t] * invN;
    float var = sums[128 + t] * invN - mean * mean;
    float sc = gamma[t] * rsqrtf(var + BN_EPS);
    ss[t] = sc;
    ss[128 + t] = beta[t] - mean * sc;
}

// ---------------- MFMA GEMM pass 2: recompute + BN apply + ReLU + residual + store --------

__global__ void __launch_bounds__(256) k_gemm_apply(const short* __restrict__ Ab,
                                                    const short* __restrict__ Wb,
                                                    const float* __restrict__ bias,
                                                    const float* __restrict__ ss,
                                                    const uint32* __restrict__ xb,
                                                    int N, float* __restrict__ out) {
    int t = threadIdx.x;
    int wave = t >> 6, lane = t & 63;
    int r0 = blockIdx.x * 64 + wave * 16;
    int lrow = lane & 15;
    int lk = (lane >> 4) * 8;

    f32x4 acc[8];
    #pragma unroll
    for (int ct = 0; ct < 8; ++ct) acc[ct] = (f32x4){0.f, 0.f, 0.f, 0.f};

    int arow = r0 + lrow;
    bool avalid = arow < N;
    #pragma unroll
    for (int kc = 0; kc < 4; ++kc) {
        bf16x8 a;
        if (avalid) a = *(const bf16x8*)&Ab[(size_t)arow * 128 + kc * 32 + lk];
        else        a = (bf16x8){0, 0, 0, 0, 0, 0, 0, 0};
        #pragma unroll
        for (int ct = 0; ct < 8; ++ct) {
            bf16x8 b = *(const bf16x8*)&Wb[(ct * 16 + lrow) * 128 + kc * 32 + lk];
            acc[ct] = __builtin_amdgcn_mfma_f32_16x16x32_bf16(a, b, acc[ct], 0, 0, 0);
        }
    }

    int orow0 = r0 + (lane >> 4) * 4;
    #pragma unroll
    for (int ct = 0; ct < 8; ++ct) {
        int ocol = ct * 16 + lrow;
        float bv = bias[ocol];
        float sc = ss[ocol];
        float sh = ss[128 + ocol];
        #pragma unroll
        for (int rr = 0; rr < 4; ++rr) {
            int r = orow0 + rr;
            if (r < N) {
                float pre = acc[ct][rr] + bv;
                float o = fmaxf(pre * sc + sh, 0.f);
                uint32 xv = xb[(size_t)r * 64 + (ocol >> 1)];
                float xr = (ocol & 1) ? bf_hi(xv) : bf_lo(xv);
                out[(size_t)r * 128 + ocol] = o + xr;
            }
        }
    }
}

// ---------------- launcher ----------------

extern "C" void kernel_launch(void* const* d_in, const int* in_sizes, int n_in,
                              void* d_out, int out_size, void* d_ws, size_t ws_size,
                              hipStream_t stream) {
    const float* x     = (const float*)d_in[0];
    const int*   ei    = (const int*)d_in[1];
    const float* W     = (const float*)d_in[2];
    const float* bias  = (const float*)d_in[3];
    const float* gamma = (const float*)d_in[4];
    const float* beta  = (const float*)d_in[5];
    float* out = (float*)d_out;

    const int D = 128;
    int N = in_sizes[0] / D;
    int E = in_sizes[1] / 2;

    int SH = 8;
    while (((N + (1 << SH) - 1) >> SH) > 1024) ++SH;
    int NB = (N + (1 << SH) - 1) >> SH;

    char* ws = (char*)d_ws;
    size_t off = 0;
    auto alloc = [&](size_t bytes) -> void* {
        void* p = ws + off;
        off += (bytes + 255) & ~(size_t)255;
        return p;
    };
    uint32* xb   = (uint32*)alloc((size_t)N * 64 * sizeof(uint32));
    uint32* aggb = (uint32*)alloc((size_t)N * 64 * sizeof(uint32));
    int2*  bpairs= (int2*)alloc((size_t)E * sizeof(int2));
    int* col     = (int*)alloc((size_t)E * sizeof(int));
    short* Wb    = (short*)alloc((size_t)D * D * sizeof(short));
    int* rowptr  = (int*)alloc((size_t)(N + 1) * sizeof(int));
    float* dinv  = (float*)alloc((size_t)N * sizeof(float));
    int nB = (N + 255) / 256;
    int* bsum    = (int*)alloc((size_t)nB * sizeof(int));
    int* bscan   = (int*)alloc((size_t)nB * sizeof(int));
    int* bbase   = (int*)alloc(1024 * sizeof(int));
    float* ss    = (float*)alloc(256 * sizeof(float));
    // zeroed region: cnt, fillc, sums, bcnt, bfill (contiguous span)
    int* cnt     = (int*)alloc((size_t)N * sizeof(int));
    int* fillc   = (int*)alloc((size_t)N * sizeof(int));
    float* sums  = (float*)alloc(256 * sizeof(float));
    int* bcnt    = (int*)alloc(1024 * sizeof(int));
    int* bfill   = (int*)alloc(1024 * sizeof(int));
    size_t zspan = (char*)(bfill + 1024) - (char*)cnt;

    hipMemsetAsync(cnt, 0, zspan, stream);

    k_convert<<<2048, 256, 0, stream>>>((const float4*)x, (uint2*)xb, N * D / 4);
    k_convert<<<16, 256, 0, stream>>>((const float4*)W, (uint2*)Wb, D * D / 4);

    k_bhist<<<256, 256, 0, stream>>>(ei + E, E, NB, SH, bcnt);
    k_scan1024<<<1, 1024, 0, stream>>>(bcnt, NB, bbase);
    k_bscatter<<<256, 256, 0, stream>>>(ei, E, NB, SH, bbase, bfill, bpairs);
    k_hist2<<<512, 256, 0, stream>>>(bpairs, E, cnt);
    k_block_sum<<<nB, 256, 0, stream>>>(cnt, N, bsum);
    k_scan1024<<<1, 1024, 0, stream>>>(bsum, nB, bscan);
    k_scan_rowptr<<<nB, 256, 0, stream>>>(cnt, bscan, N, E, rowptr, dinv);
    k_fill2<<<512, 256, 0, stream>>>(bpairs, E, rowptr, fillc, col);

    k_agg<<<(N + 3) / 4, 256, 0, stream>>>(xb, rowptr, col, dinv, aggb, N);

    k_gemm_stats<<<(N + 63) / 64, 256, 0, stream>>>((const short*)aggb, Wb, bias, N, sums);
    k_bnparams<<<1, 128, 0, stream>>>(sums, gamma, beta, 1.0f / (float)N, ss);
    k_gemm_apply<<<(N + 63) / 64, 256, 0, stream>>>((const short*)aggb, Wb, bias, ss, xb, N, out);
}

// Round 4
// 313.215 us; speedup vs baseline: 1.6523x; 1.0162x over previous
//
#include <hip/hip_runtime.h>

#define BN_EPS 1e-5f

typedef unsigned int uint32;
typedef __attribute__((ext_vector_type(8))) short bf16x8;
typedef __attribute__((ext_vector_type(4))) float f32x4;

__device__ __forceinline__ float bf_lo(uint32 v) {
    union { uint32 u; float f; } c; c.u = v << 16; return c.f;
}
__device__ __forceinline__ float bf_hi(uint32 v) {
    union { uint32 u; float f; } c; c.u = v & 0xffff0000u; return c.f;
}
__device__ __forceinline__ uint32 f2bf(float f) {  // RNE, low 16 bits
    union { float f; uint32 u; } c; c.f = f;
    uint32 u = c.u;
    u += 0x7fffu + ((u >> 16) & 1u);
    return u >> 16;
}

// ---------------- fp32 -> bf16 ----------------

__global__ void k_convert(const float4* __restrict__ in, uint2* __restrict__ outb, int total4) {
    int i = blockIdx.x * blockDim.x + threadIdx.x;
    int stride = gridDim.x * blockDim.x;
    for (; i < total4; i += stride) {
        float4 v = in[i];
        uint2 o;
        o.x = f2bf(v.x) | (f2bf(v.y) << 16);
        o.y = f2bf(v.z) | (f2bf(v.w) << 16);
        outb[i] = o;
    }
}

// ---------------- bucket partition (counting sort by dst>>SH) ----------------

__global__ void __launch_bounds__(256) k_bhist(const int* __restrict__ dst, int E, int NB, int SH,
                                               int* __restrict__ bcnt) {
    __shared__ int h[1024];
    for (int i = threadIdx.x; i < NB; i += 256) h[i] = 0;
    __syncthreads();
    int idx = blockIdx.x * 256 + threadIdx.x;
    int stride = gridDim.x * 256;
    for (int e = idx; e < E; e += stride) atomicAdd(&h[dst[e] >> SH], 1);
    __syncthreads();
    for (int i = threadIdx.x; i < NB; i += 256)
        if (h[i]) atomicAdd(&bcnt[i], h[i]);
}

__global__ void k_scan1024(const int* __restrict__ in, int n, int* __restrict__ outExcl) {
    __shared__ int s[1024];
    int t = threadIdx.x;
    int v = (t < n) ? in[t] : 0;
    s[t] = v;
    __syncthreads();
    for (int off = 1; off < 1024; off <<= 1) {
        int add = (t >= off) ? s[t - off] : 0;
        __syncthreads();
        s[t] += add;
        __syncthreads();
    }
    if (t < n) outExcl[t] = s[t] - v;
}

__global__ void __launch_bounds__(256) k_bscatter(const int* __restrict__ ei, int E, int NB, int SH,
                                                  const int* __restrict__ bbase,
                                                  int* __restrict__ bfill,
                                                  int2* __restrict__ bpairs) {
    __shared__ int h[1024];
    int nBlk = gridDim.x;
    int c0 = (int)((long long)blockIdx.x * E / nBlk);
    int c1 = (int)((long long)(blockIdx.x + 1) * E / nBlk);
    for (int i = threadIdx.x; i < NB; i += 256) h[i] = 0;
    __syncthreads();
    for (int e = c0 + threadIdx.x; e < c1; e += 256)
        atomicAdd(&h[ei[E + e] >> SH], 1);
    __syncthreads();
    for (int i = threadIdx.x; i < NB; i += 256) {
        int c = h[i];
        if (c > 0) h[i] = bbase[i] + atomicAdd(&bfill[i], c);
    }
    __syncthreads();
    for (int e = c0 + threadIdx.x; e < c1; e += 256) {
        int s = ei[e];
        int d = ei[E + e];
        int pos = atomicAdd(&h[d >> SH], 1);
        bpairs[pos] = make_int2(s, d);
    }
}

// ---------------- degree histogram over bucket-grouped pairs ----------------

__global__ void __launch_bounds__(256) k_hist2(const int2* __restrict__ bpairs, int E,
                                               int* __restrict__ cnt) {
    int nBlk = gridDim.x;
    int c0 = (int)((long long)blockIdx.x * E / nBlk);
    int c1 = (int)((long long)(blockIdx.x + 1) * E / nBlk);
    for (int e = c0 + threadIdx.x; e < c1; e += 256)
        atomicAdd(&cnt[bpairs[e].y], 1);
}

__global__ void k_block_sum(const int* __restrict__ cnt, int N, int* __restrict__ bsum) {
    __shared__ int s[256];
    int i = blockIdx.x * 256 + threadIdx.x;
    int v = (i < N) ? cnt[i] : 0;
    s[threadIdx.x] = v;
    __syncthreads();
    for (int off = 128; off > 0; off >>= 1) {
        if (threadIdx.x < off) s[threadIdx.x] += s[threadIdx.x + off];
        __syncthreads();
    }
    if (threadIdx.x == 0) bsum[blockIdx.x] = s[0];
}

__global__ void k_scan_rowptr(const int* __restrict__ cnt, const int* __restrict__ bscan,
                              int N, int E, int* __restrict__ rowptr,
                              float* __restrict__ dinv) {
    __shared__ int s[256];
    int t = threadIdx.x;
    int i = blockIdx.x * 256 + t;
    int v = (i < N) ? cnt[i] : 0;
    s[t] = v;
    __syncthreads();
    for (int off = 1; off < 256; off <<= 1) {
        int add = (t >= off) ? s[t - off] : 0;
        __syncthreads();
        s[t] += add;
        __syncthreads();
    }
    if (i < N) {
        rowptr[i] = bscan[blockIdx.x] + s[t] - v;  // exclusive
        dinv[i] = rsqrtf((float)(v + 1));           // deg incl. self-loop
    }
    if (i == 0) rowptr[N] = E;
}

// ---------------- CSR fill: colw[pos] = {src, dinv[src]} ----------------

__global__ void __launch_bounds__(256) k_fill2(const int2* __restrict__ bpairs, int E,
                                               const int* __restrict__ rowptr,
                                               const float* __restrict__ dinv,
                                               int* __restrict__ fillc, int2* __restrict__ colw) {
    int nBlk = gridDim.x;
    int c0 = (int)((long long)blockIdx.x * E / nBlk);
    int c1 = (int)((long long)(blockIdx.x + 1) * E / nBlk);
    for (int e = c0 + threadIdx.x; e < c1; e += 256) {
        int2 p = bpairs[e];
        float w = dinv[p.x];
        int pos = rowptr[p.y] + atomicAdd(&fillc[p.y], 1);
        colw[pos] = make_int2(p.x, __float_as_int(w));
    }
}

// ---------------- aggregation: wave-per-node, 4 edges/gather-instr, 8 in flight -------------
// aggx[i] = di*(di*x[i] + sum_j dinv[j]*x[j])

__global__ void __launch_bounds__(256) k_agg(const uint32* __restrict__ xb,
                                             const int* __restrict__ rowptr,
                                             const int2* __restrict__ colw,
                                             const float* __restrict__ dinv,
                                             uint32* __restrict__ aggb, int N) {
    int wid = blockIdx.x * 4 + (threadIdx.x >> 6);
    if (wid >= N) return;
    int lane = threadIdx.x & 63;
    int g = lane >> 4;        // edge slot within group of 4
    int c = lane & 15;        // 16-byte column chunk

    float acc[8];
    #pragma unroll
    for (int j = 0; j < 8; ++j) acc[j] = 0.f;

    int e0 = rowptr[wid], e1 = rowptr[wid + 1];
    for (int e = e0; e < e1; e += 8) {
        int i0 = e + g, i1 = e + 4 + g;
        float w0 = 0.f, w1 = 0.f;
        int s0 = 0, s1 = 0;
        if (i0 < e1) { int2 p = colw[i0]; s0 = p.x; w0 = __int_as_float(p.y); }
        if (i1 < e1) { int2 p = colw[i1]; s1 = p.x; w1 = __int_as_float(p.y); }
        uint4 v0 = *(const uint4*)&xb[(size_t)s0 * 64 + c * 4];
        uint4 v1 = *(const uint4*)&xb[(size_t)s1 * 64 + c * 4];
        acc[0] += w0 * bf_lo(v0.x); acc[1] += w0 * bf_hi(v0.x);
        acc[2] += w0 * bf_lo(v0.y); acc[3] += w0 * bf_hi(v0.y);
        acc[4] += w0 * bf_lo(v0.z); acc[5] += w0 * bf_hi(v0.z);
        acc[6] += w0 * bf_lo(v0.w); acc[7] += w0 * bf_hi(v0.w);
        acc[0] += w1 * bf_lo(v1.x); acc[1] += w1 * bf_hi(v1.x);
        acc[2] += w1 * bf_lo(v1.y); acc[3] += w1 * bf_hi(v1.y);
        acc[4] += w1 * bf_lo(v1.z); acc[5] += w1 * bf_hi(v1.z);
        acc[6] += w1 * bf_lo(v1.w); acc[7] += w1 * bf_hi(v1.w);
    }
    #pragma unroll
    for (int j = 0; j < 8; ++j) {
        acc[j] += __shfl_xor(acc[j], 16);
        acc[j] += __shfl_xor(acc[j], 32);
    }
    if (g == 0) {
        float di = dinv[wid];
        uint4 sv = *(const uint4*)&xb[(size_t)wid * 64 + c * 4];
        uint4 o;
        float a0, a1;
        a0 = di * (di * bf_lo(sv.x) + acc[0]);
        a1 = di * (di * bf_hi(sv.x) + acc[1]);
        o.x = f2bf(a0) | (f2bf(a1) << 16);
        a0 = di * (di * bf_lo(sv.y) + acc[2]);
        a1 = di * (di * bf_hi(sv.y) + acc[3]);
        o.y = f2bf(a0) | (f2bf(a1) << 16);
        a0 = di * (di * bf_lo(sv.z) + acc[4]);
        a1 = di * (di * bf_hi(sv.z) + acc[5]);
        o.z = f2bf(a0) | (f2bf(a1) << 16);
        a0 = di * (di * bf_lo(sv.w) + acc[6]);
        a1 = di * (di * bf_hi(sv.w) + acc[7]);
        o.w = f2bf(a0) | (f2bf(a1) << 16);
        *(uint4*)&aggb[(size_t)wid * 64 + c * 4] = o;
    }
}

// ---------------- persistent MFMA GEMM, W staged in LDS (XOR-swizzled) ----------------
// block = 256 = 4 waves; tile = 64 rows; wave: 16 rows x 128 cols; K=128 in 4 chunks.
// W lds layout: byte = row*256 + ((chunk16*16) ^ ((row&7)<<4))  -> <=2-way bank conflicts.

#define STAGE_W()                                                            \
    for (int m = threadIdx.x; m < 2048; m += 256) {                          \
        int row = m >> 4, cc = m & 15;                                       \
        uint4 v = *(const uint4*)&Wb[row * 128 + cc * 8];                    \
        *(uint4*)((char*)wlds + row * 256 + ((cc * 16) ^ ((row & 7) << 4))) = v; \
    }

#define MFMA_TILE(acc, tile)                                                 \
    {                                                                        \
        int arow = (tile) * 64 + wave * 16 + lrow;                           \
        bool avalid = arow < N;                                              \
        _Pragma("unroll")                                                    \
        for (int kc = 0; kc < 4; ++kc) {                                     \
            bf16x8 a;                                                        \
            if (avalid) a = *(const bf16x8*)&Ab[(size_t)arow * 128 + kc * 32 + g * 8]; \
            else        a = (bf16x8){0, 0, 0, 0, 0, 0, 0, 0};                \
            _Pragma("unroll")                                                \
            for (int ct = 0; ct < 8; ++ct) {                                 \
                int row = ct * 16 + lrow;                                    \
                const bf16x8 b = *(const bf16x8*)((const char*)wlds + row * 256 \
                                   + ((kc * 64 + g * 16) ^ ((row & 7) << 4))); \
                acc[ct] = __builtin_amdgcn_mfma_f32_16x16x32_bf16(a, b, acc[ct], 0, 0, 0); \
            }                                                                \
        }                                                                    \
    }

__global__ void __launch_bounds__(256) k_gemm_stats(const short* __restrict__ Ab,
                                                    const short* __restrict__ Wb,
                                                    const float* __restrict__ bias,
                                                    int N, int ntiles,
                                                    float* __restrict__ partials) {
    __shared__ uint32 wlds[8192];
    __shared__ float red[1024];
    STAGE_W();
    __syncthreads();

    int t = threadIdx.x;
    int wave = t >> 6, lane = t & 63;
    int lrow = lane & 15, g = lane >> 4;

    float bv[8];
    #pragma unroll
    for (int ct = 0; ct < 8; ++ct) bv[ct] = bias[ct * 16 + lrow];

    float s[8], sq[8];
    #pragma unroll
    for (int ct = 0; ct < 8; ++ct) { s[ct] = 0.f; sq[ct] = 0.f; }

    for (int tile = blockIdx.x; tile < ntiles; tile += gridDim.x) {
        f32x4 acc[8];
        #pragma unroll
        for (int ct = 0; ct < 8; ++ct) acc[ct] = (f32x4){0.f, 0.f, 0.f, 0.f};
        MFMA_TILE(acc, tile);
        int orow0 = tile * 64 + wave * 16 + g * 4;
        #pragma unroll
        for (int ct = 0; ct < 8; ++ct) {
            #pragma unroll
            for (int rr = 0; rr < 4; ++rr) {
                if (orow0 + rr < N) {
                    float o = acc[ct][rr] + bv[ct];
                    s[ct] += o; sq[ct] += o * o;
                }
            }
        }
    }
    #pragma unroll
    for (int ct = 0; ct < 8; ++ct) {
        s[ct] += __shfl_xor(s[ct], 16); sq[ct] += __shfl_xor(sq[ct], 16);
        s[ct] += __shfl_xor(s[ct], 32); sq[ct] += __shfl_xor(sq[ct], 32);
    }
    if (lane < 16) {
        #pragma unroll
        for (int ct = 0; ct < 8; ++ct) {
            int col = ct * 16 + lrow;
            red[wave * 256 + col] = s[ct];
            red[wave * 256 + 128 + col] = sq[ct];
        }
    }
    __syncthreads();
    if (t < 256)
        partials[blockIdx.x * 256 + t] = red[t] + red[256 + t] + red[512 + t] + red[768 + t];
}

__global__ void k_bnparams(const float* __restrict__ partials, int nblk,
                           const float* __restrict__ gamma, const float* __restrict__ beta,
                           float invN, float* __restrict__ ss) {
    __shared__ float tot[256];
    int t = threadIdx.x;  // 256
    float v = 0.f;
    for (int b = 0; b < nblk; ++b) v += partials[b * 256 + t];
    tot[t] = v;
    __syncthreads();
    if (t < 128) {
        float mean = tot[t] * invN;
        float var = tot[128 + t] * invN - mean * mean;
        float sc = gamma[t] * rsqrtf(var + BN_EPS);
        ss[t] = sc;
        ss[128 + t] = beta[t] - mean * sc;
    }
}

__global__ void __launch_bounds__(256) k_gemm_apply(const short* __restrict__ Ab,
                                                    const short* __restrict__ Wb,
                                                    const float* __restrict__ bias,
                                                    const float* __restrict__ ss,
                                                    const uint32* __restrict__ xb,
                                                    int N, int ntiles,
                                                    float* __restrict__ out) {
    __shared__ uint32 wlds[8192];
    STAGE_W();
    __syncthreads();

    int t = threadIdx.x;
    int wave = t >> 6, lane = t & 63;
    int lrow = lane & 15, g = lane >> 4;

    float bv[8], scv[8], shv[8];
    #pragma unroll
    for (int ct = 0; ct < 8; ++ct) {
        int col = ct * 16 + lrow;
        bv[ct] = bias[col]; scv[ct] = ss[col]; shv[ct] = ss[128 + col];
    }

    for (int tile = blockIdx.x; tile < ntiles; tile += gridDim.x) {
        f32x4 acc[8];
        #pragma unroll
        for (int ct = 0; ct < 8; ++ct) acc[ct] = (f32x4){0.f, 0.f, 0.f, 0.f};
        MFMA_TILE(acc, tile);
        int orow0 = tile * 64 + wave * 16 + g * 4;
        #pragma unroll
        for (int ct = 0; ct < 8; ++ct) {
            int ocol = ct * 16 + lrow;
            #pragma unroll
            for (int rr = 0; rr < 4; ++rr) {
                int r = orow0 + rr;
                if (r < N) {
                    float pre = acc[ct][rr] + bv[ct];
                    float o = fmaxf(pre * scv[ct] + shv[ct], 0.f);
                    uint32 xv = xb[(size_t)r * 64 + (ocol >> 1)];
                    float xr = (ocol & 1) ? bf_hi(xv) : bf_lo(xv);
                    out[(size_t)r * 128 + ocol] = o + xr;
                }
            }
        }
    }
}

// ---------------- launcher ----------------

extern "C" void kernel_launch(void* const* d_in, const int* in_sizes, int n_in,
                              void* d_out, int out_size, void* d_ws, size_t ws_size,
                              hipStream_t stream) {
    const float* x     = (const float*)d_in[0];
    const int*   ei    = (const int*)d_in[1];
    const float* W     = (const float*)d_in[2];
    const float* bias  = (const float*)d_in[3];
    const float* gamma = (const float*)d_in[4];
    const float* beta  = (const float*)d_in[5];
    float* out = (float*)d_out;

    const int D = 128;
    int N = in_sizes[0] / D;
    int E = in_sizes[1] / 2;

    int SH = 8;
    while (((N + (1 << SH) - 1) >> SH) > 1024) ++SH;
    int NB = (N + (1 << SH) - 1) >> SH;

    const int GSTATS = 256;   // persistent gemm grids
    const int GAPPLY = 512;

    char* ws = (char*)d_ws;
    size_t off = 0;
    auto alloc = [&](size_t bytes) -> void* {
        void* p = ws + off;
        off += (bytes + 255) & ~(size_t)255;
        return p;
    };
    uint32* xb   = (uint32*)alloc((size_t)N * 64 * sizeof(uint32));
    uint32* aggb = (uint32*)alloc((size_t)N * 64 * sizeof(uint32));
    int2*  bpairs= (int2*)alloc((size_t)E * sizeof(int2));
    int2*  colw  = (int2*)alloc((size_t)E * sizeof(int2));
    short* Wb    = (short*)alloc((size_t)D * D * sizeof(short));
    int* rowptr  = (int*)alloc((size_t)(N + 1) * sizeof(int));
    float* dinv  = (float*)alloc((size_t)N * sizeof(float));
    int nB = (N + 255) / 256;
    int* bsum    = (int*)alloc((size_t)nB * sizeof(int));
    int* bscan   = (int*)alloc((size_t)nB * sizeof(int));
    int* bbase   = (int*)alloc(1024 * sizeof(int));
    float* ss    = (float*)alloc(256 * sizeof(float));
    float* partials = (float*)alloc((size_t)GSTATS * 256 * sizeof(float));
    // zeroed region: cnt, fillc, bcnt, bfill (contiguous span)
    int* cnt     = (int*)alloc((size_t)N * sizeof(int));
    int* fillc   = (int*)alloc((size_t)N * sizeof(int));
    int* bcnt    = (int*)alloc(1024 * sizeof(int));
    int* bfill   = (int*)alloc(1024 * sizeof(int));
    size_t zspan = (char*)(bfill + 1024) - (char*)cnt;

    hipMemsetAsync(cnt, 0, zspan, stream);

    k_convert<<<2048, 256, 0, stream>>>((const float4*)x, (uint2*)xb, N * D / 4);
    k_convert<<<16, 256, 0, stream>>>((const float4*)W, (uint2*)Wb, D * D / 4);

    k_bhist<<<256, 256, 0, stream>>>(ei + E, E, NB, SH, bcnt);
    k_scan1024<<<1, 1024, 0, stream>>>(bcnt, NB, bbase);
    k_bscatter<<<256, 256, 0, stream>>>(ei, E, NB, SH, bbase, bfill, bpairs);
    k_hist2<<<512, 256, 0, stream>>>(bpairs, E, cnt);
    k_block_sum<<<nB, 256, 0, stream>>>(cnt, N, bsum);
    k_scan1024<<<1, 1024, 0, stream>>>(bsum, nB, bscan);
    k_scan_rowptr<<<nB, 256, 0, stream>>>(cnt, bscan, N, E, rowptr, dinv);
    k_fill2<<<512, 256, 0, stream>>>(bpairs, E, rowptr, dinv, fillc, colw);

    k_agg<<<(N + 3) / 4, 256, 0, stream>>>(xb, rowptr, colw, dinv, aggb, N);

    int ntiles = (N + 63) / 64;
    k_gemm_stats<<<GSTATS, 256, 0, stream>>>((const short*)aggb, Wb, bias, N, ntiles, partials);
    k_bnparams<<<1, 256, 0, stream>>>(partials, GSTATS, gamma, beta, 1.0f / (float)N, ss);
    k_gemm_apply<<<GAPPLY, 256, 0, stream>>>((const short*)aggb, Wb, bias, ss, xb, N, ntiles, out);
}

// Round 5
// 242.843 us; speedup vs baseline: 2.1311x; 1.2898x over previous
//
#include <hip/hip_runtime.h>
#include <hip/hip_fp16.h>

#define BN_EPS 1e-5f

typedef unsigned int uint32;
typedef __attribute__((ext_vector_type(8))) _Float16 f16x8;
typedef __attribute__((ext_vector_type(4))) float f32x4;

union H2U { __half2 h; uint32 u; };

__device__ __forceinline__ __half2 u2h(uint32 u) { H2U c; c.u = u; return c.h; }
__device__ __forceinline__ uint32 h2u(__half2 h) { H2U c; c.h = h; return c.u; }
__device__ __forceinline__ uint32 pack2h(float a, float b) {
    return h2u(__halves2half2(__float2half_rn(a), __float2half_rn(b)));
}
__device__ __forceinline__ float h2lo(uint32 u) {
    return __half2float(__ushort_as_half((unsigned short)(u & 0xffffu)));
}
__device__ __forceinline__ float h2hi(uint32 u) {
    return __half2float(__ushort_as_half((unsigned short)(u >> 16)));
}

// ---------------- prep: convert x,W to fp16 + bucket histogram of dst ----------------

__global__ void __launch_bounds__(256) k_prep(const float4* __restrict__ x4, int nx4,
                                              const float4* __restrict__ w4, int nw4,
                                              const int* __restrict__ dst, int E, int NB,
                                              uint2* __restrict__ xh4, uint2* __restrict__ wh4,
                                              int* __restrict__ bcnt) {
    __shared__ int h[1024];
    int t = threadIdx.x;
    if (blockIdx.x < 256) {  // bucket histogram over an E-slice
        for (int i = t; i < NB; i += 256) h[i] = 0;
        __syncthreads();
        int c0 = (int)((long long)blockIdx.x * E / 256);
        int c1 = (int)((long long)(blockIdx.x + 1) * E / 256);
        for (int e = c0 + t; e < c1; e += 256) atomicAdd(&h[dst[e] >> 8], 1);
        __syncthreads();
        for (int i = t; i < NB; i += 256)
            if (h[i]) atomicAdd(&bcnt[i], h[i]);
    }
    int idx = blockIdx.x * 256 + t;
    int stride = gridDim.x * 256;
    for (int i = idx; i < nx4; i += stride) {
        float4 v = x4[i];
        xh4[i] = make_uint2(pack2h(v.x, v.y), pack2h(v.z, v.w));
    }
    for (int i = idx; i < nw4; i += stride) {
        float4 v = w4[i];
        wh4[i] = make_uint2(pack2h(v.x, v.y), pack2h(v.z, v.w));
    }
}

// ---------------- exclusive scan of bucket counts (1 block) ----------------

__global__ void k_scan1024(const int* __restrict__ in, int n, int* __restrict__ outExcl) {
    __shared__ int s[1024];
    int t = threadIdx.x;
    int v = (t < n) ? in[t] : 0;
    s[t] = v;
    __syncthreads();
    for (int off = 1; off < 1024; off <<= 1) {
        int add = (t >= off) ? s[t - off] : 0;
        __syncthreads();
        s[t] += add;
        __syncthreads();
    }
    if (t < n) outExcl[t] = s[t] - v;
    if (t == n - 1) outExcl[n] = s[t];  // total = E
}

// ---------------- bucket scatter: bpack[pos] = (localDst<<24) | src ----------------

__global__ void __launch_bounds__(256) k_bscatter(const int* __restrict__ ei, int E, int NB,
                                                  const int* __restrict__ bbase,
                                                  int* __restrict__ bfill,
                                                  uint32* __restrict__ bpack) {
    __shared__ int h[1024];
    int t = threadIdx.x;
    int c0 = (int)((long long)blockIdx.x * E / gridDim.x);
    int c1 = (int)((long long)(blockIdx.x + 1) * E / gridDim.x);
    for (int i = t; i < NB; i += 256) h[i] = 0;
    __syncthreads();
    for (int e = c0 + t; e < c1; e += 256)
        atomicAdd(&h[ei[E + e] >> 8], 1);
    __syncthreads();
    for (int i = t; i < NB; i += 256) {
        int c = h[i];
        if (c > 0) h[i] = bbase[i] + atomicAdd(&bfill[i], c);
    }
    __syncthreads();
    for (int e = c0 + t; e < c1; e += 256) {
        int s = ei[e];
        int d = ei[E + e];
        int b = d >> 8;
        int pos = atomicAdd(&h[b], 1);
        bpack[pos] = ((uint32)(d & 255) << 24) | (uint32)s;
    }
}

// ---------------- per-bucket CSR: count, scan, rowptr, dinv(fp16x2), col ----------------

__global__ void __launch_bounds__(256) k_csr(const uint32* __restrict__ bpack,
                                             const int* __restrict__ bbase,
                                             int N, int E,
                                             int* __restrict__ rowptr,
                                             uint32* __restrict__ dpk,
                                             int* __restrict__ col) {
    __shared__ int h[256], s[256], cur[256];
    int b = blockIdx.x;
    int t = threadIdx.x;
    int e0 = bbase[b], e1 = bbase[b + 1];
    h[t] = 0;
    __syncthreads();
    for (int e = e0 + t; e < e1; e += 256)
        atomicAdd(&h[bpack[e] >> 24], 1);
    __syncthreads();
    int cnt = h[t];
    s[t] = cnt;
    __syncthreads();
    for (int off = 1; off < 256; off <<= 1) {
        int add = (t >= off) ? s[t - off] : 0;
        __syncthreads();
        s[t] += add;
        __syncthreads();
    }
    int excl = s[t] - cnt;
    int node = (b << 8) + t;
    if (node < N) {
        rowptr[node] = e0 + excl;
        float dv = rsqrtf((float)(cnt + 1));
        dpk[node] = pack2h(dv, dv);
        if (node == N - 1) rowptr[N] = E;
    }
    cur[t] = e0 + excl;
    __syncthreads();
    for (int e = e0 + t; e < e1; e += 256) {
        uint32 p = bpack[e];
        int pos = atomicAdd(&cur[p >> 24], 1);
        col[pos] = (int)(p & 0xffffffu);
    }
}

// ---------------- aggregation: wave-per-node, fp16 pk_fma, 16 edges in flight ----------
// aggx[i] = di*(di*x[i] + sum_j dinv[j]*x[j])

#define EDGE_FMA(vv, ww)                                   \
    acc0 = __hfma2(u2h((vv).x), u2h(ww), acc0);            \
    acc1 = __hfma2(u2h((vv).y), u2h(ww), acc1);            \
    acc2 = __hfma2(u2h((vv).z), u2h(ww), acc2);            \
    acc3 = __hfma2(u2h((vv).w), u2h(ww), acc3);

__global__ void __launch_bounds__(256) k_agg(const uint32* __restrict__ xh,
                                             const int* __restrict__ rowptr,
                                             const int* __restrict__ col,
                                             const uint32* __restrict__ dpk,
                                             uint32* __restrict__ aggh, int N) {
    int wid = blockIdx.x * 4 + (threadIdx.x >> 6);
    if (wid >= N) return;
    int lane = threadIdx.x & 63;
    int g = lane >> 4, c = lane & 15;

    __half2 z = __float2half2_rn(0.f);
    __half2 acc0 = z, acc1 = z, acc2 = z, acc3 = z;

    int e0 = rowptr[wid], e1 = rowptr[wid + 1];
    int e = e0;
    for (; e + 16 <= e1; e += 16) {
        int i0 = e + g, i1 = e + 4 + g, i2 = e + 8 + g, i3 = e + 12 + g;
        int s0 = col[i0], s1 = col[i1], s2 = col[i2], s3 = col[i3];
        uint32 w0 = dpk[s0], w1 = dpk[s1], w2 = dpk[s2], w3 = dpk[s3];
        uint4 v0 = *(const uint4*)&xh[(size_t)s0 * 64 + c * 4];
        uint4 v1 = *(const uint4*)&xh[(size_t)s1 * 64 + c * 4];
        uint4 v2 = *(const uint4*)&xh[(size_t)s2 * 64 + c * 4];
        uint4 v3 = *(const uint4*)&xh[(size_t)s3 * 64 + c * 4];
        EDGE_FMA(v0, w0); EDGE_FMA(v1, w1); EDGE_FMA(v2, w2); EDGE_FMA(v3, w3);
    }
    if (e < e1) {  // masked tail, <=15 edges
        int i0 = e + g, i1 = e + 4 + g, i2 = e + 8 + g, i3 = e + 12 + g;
        int s0 = 0, s1 = 0, s2 = 0, s3 = 0;
        uint32 w0 = 0, w1 = 0, w2 = 0, w3 = 0;
        if (i0 < e1) { s0 = col[i0]; w0 = dpk[s0]; }
        if (i1 < e1) { s1 = col[i1]; w1 = dpk[s1]; }
        if (i2 < e1) { s2 = col[i2]; w2 = dpk[s2]; }
        if (i3 < e1) { s3 = col[i3]; w3 = dpk[s3]; }
        uint4 v0 = *(const uint4*)&xh[(size_t)s0 * 64 + c * 4];
        uint4 v1 = *(const uint4*)&xh[(size_t)s1 * 64 + c * 4];
        uint4 v2 = *(const uint4*)&xh[(size_t)s2 * 64 + c * 4];
        uint4 v3 = *(const uint4*)&xh[(size_t)s3 * 64 + c * 4];
        EDGE_FMA(v0, w0); EDGE_FMA(v1, w1); EDGE_FMA(v2, w2); EDGE_FMA(v3, w3);
    }
    // reduce across the 4 edge-groups (lanes xor 16, 32)
    uint32 u;
    u = __shfl_xor(h2u(acc0), 16); acc0 = __hadd2(acc0, u2h(u));
    u = __shfl_xor(h2u(acc0), 32); acc0 = __hadd2(acc0, u2h(u));
    u = __shfl_xor(h2u(acc1), 16); acc1 = __hadd2(acc1, u2h(u));
    u = __shfl_xor(h2u(acc1), 32); acc1 = __hadd2(acc1, u2h(u));
    u = __shfl_xor(h2u(acc2), 16); acc2 = __hadd2(acc2, u2h(u));
    u = __shfl_xor(h2u(acc2), 32); acc2 = __hadd2(acc2, u2h(u));
    u = __shfl_xor(h2u(acc3), 16); acc3 = __hadd2(acc3, u2h(u));
    u = __shfl_xor(h2u(acc3), 32); acc3 = __hadd2(acc3, u2h(u));

    if (g == 0) {
        float di = h2lo(dpk[wid]);
        uint4 sv = *(const uint4*)&xh[(size_t)wid * 64 + c * 4];
        uint4 o;
        o.x = pack2h(di * (di * h2lo(sv.x) + __low2float(acc0)),
                     di * (di * h2hi(sv.x) + __high2float(acc0)));
        o.y = pack2h(di * (di * h2lo(sv.y) + __low2float(acc1)),
                     di * (di * h2hi(sv.y) + __high2float(acc1)));
        o.z = pack2h(di * (di * h2lo(sv.z) + __low2float(acc2)),
                     di * (di * h2hi(sv.z) + __high2float(acc2)));
        o.w = pack2h(di * (di * h2lo(sv.w) + __low2float(acc3)),
                     di * (di * h2hi(sv.w) + __high2float(acc3)));
        *(uint4*)&aggh[(size_t)wid * 64 + c * 4] = o;
    }
}

// ---------------- persistent MFMA GEMM (fp16), W staged in LDS (XOR-swizzled) ----------

#define STAGE_W()                                                            \
    for (int m = threadIdx.x; m < 2048; m += 256) {                          \
        int row = m >> 4, cc = m & 15;                                       \
        uint4 v = *(const uint4*)&Wh[row * 128 + cc * 8];                    \
        *(uint4*)((char*)wlds + row * 256 + ((cc * 16) ^ ((row & 7) << 4))) = v; \
    }

#define MFMA_TILE(acc, tile)                                                 \
    {                                                                        \
        int arow = (tile) * 64 + wave * 16 + lrow;                           \
        bool avalid = arow < N;                                              \
        _Pragma("unroll")                                                    \
        for (int kc = 0; kc < 4; ++kc) {                                     \
            f16x8 a;                                                         \
            if (avalid) a = *(const f16x8*)&Ah[(size_t)arow * 128 + kc * 32 + g * 8]; \
            else        a = (f16x8){0, 0, 0, 0, 0, 0, 0, 0};                 \
            _Pragma("unroll")                                                \
            for (int ct = 0; ct < 8; ++ct) {                                 \
                int row = ct * 16 + lrow;                                    \
                const f16x8 bfr = *(const f16x8*)((const char*)wlds + row * 256 \
                                   + ((kc * 64 + g * 16) ^ ((row & 7) << 4))); \
                acc[ct] = __builtin_amdgcn_mfma_f32_16x16x32_f16(a, bfr, acc[ct], 0, 0, 0); \
            }                                                                \
        }                                                                    \
    }

__global__ void __launch_bounds__(256) k_gemm_stats(const _Float16* __restrict__ Ah,
                                                    const _Float16* __restrict__ Wh,
                                                    const float* __restrict__ bias,
                                                    int N, int ntiles,
                                                    float* __restrict__ partials) {
    __shared__ uint32 wlds[8192];
    __shared__ float red[1024];
    STAGE_W();
    __syncthreads();

    int t = threadIdx.x;
    int wave = t >> 6, lane = t & 63;
    int lrow = lane & 15, g = lane >> 4;

    float bv[8];
    #pragma unroll
    for (int ct = 0; ct < 8; ++ct) bv[ct] = bias[ct * 16 + lrow];

    float s[8], sq[8];
    #pragma unroll
    for (int ct = 0; ct < 8; ++ct) { s[ct] = 0.f; sq[ct] = 0.f; }

    for (int tile = blockIdx.x; tile < ntiles; tile += gridDim.x) {
        f32x4 acc[8];
        #pragma unroll
        for (int ct = 0; ct < 8; ++ct) acc[ct] = (f32x4){0.f, 0.f, 0.f, 0.f};
        MFMA_TILE(acc, tile);
        int orow0 = tile * 64 + wave * 16 + g * 4;
        #pragma unroll
        for (int ct = 0; ct < 8; ++ct) {
            #pragma unroll
            for (int rr = 0; rr < 4; ++rr) {
                if (orow0 + rr < N) {
                    float o = acc[ct][rr] + bv[ct];
                    s[ct] += o; sq[ct] += o * o;
                }
            }
        }
    }
    #pragma unroll
    for (int ct = 0; ct < 8; ++ct) {
        s[ct] += __shfl_xor(s[ct], 16); sq[ct] += __shfl_xor(sq[ct], 16);
        s[ct] += __shfl_xor(s[ct], 32); sq[ct] += __shfl_xor(sq[ct], 32);
    }
    if (lane < 16) {
        #pragma unroll
        for (int ct = 0; ct < 8; ++ct) {
            int colI = ct * 16 + lrow;
            red[wave * 256 + colI] = s[ct];
            red[wave * 256 + 128 + colI] = sq[ct];
        }
    }
    __syncthreads();
    if (t < 256)
        partials[blockIdx.x * 256 + t] = red[t] + red[256 + t] + red[512 + t] + red[768 + t];
}

__global__ void k_bnparams(const float* __restrict__ partials, int nblk,
                           const float* __restrict__ gamma, const float* __restrict__ beta,
                           float invN, float* __restrict__ ss) {
    __shared__ float tot[256];
    int t = threadIdx.x;  // 256
    float v = 0.f;
    for (int b = 0; b < nblk; ++b) v += partials[b * 256 + t];
    tot[t] = v;
    __syncthreads();
    if (t < 128) {
        float mean = tot[t] * invN;
        float var = tot[128 + t] * invN - mean * mean;
        float sc = gamma[t] * rsqrtf(var + BN_EPS);
        ss[t] = sc;
        ss[128 + t] = beta[t] - mean * sc;
    }
}

__global__ void __launch_bounds__(256) k_gemm_apply(const _Float16* __restrict__ Ah,
                                                    const _Float16* __restrict__ Wh,
                                                    const float* __restrict__ bias,
                                                    const float* __restrict__ ss,
                                                    const uint32* __restrict__ xh,
                                                    int N, int ntiles,
                                                    float* __restrict__ out) {
    __shared__ uint32 wlds[8192];
    STAGE_W();
    __syncthreads();

    int t = threadIdx.x;
    int wave = t >> 6, lane = t & 63;
    int lrow = lane & 15, g = lane >> 4;

    float bv[8], scv[8], shv[8];
    #pragma unroll
    for (int ct = 0; ct < 8; ++ct) {
        int colI = ct * 16 + lrow;
        bv[ct] = bias[colI]; scv[ct] = ss[colI]; shv[ct] = ss[128 + colI];
    }

    for (int tile = blockIdx.x; tile < ntiles; tile += gridDim.x) {
        f32x4 acc[8];
        #pragma unroll
        for (int ct = 0; ct < 8; ++ct) acc[ct] = (f32x4){0.f, 0.f, 0.f, 0.f};
        MFMA_TILE(acc, tile);
        int orow0 = tile * 64 + wave * 16 + g * 4;
        #pragma unroll
        for (int ct = 0; ct < 8; ++ct) {
            int ocol = ct * 16 + lrow;
            #pragma unroll
            for (int rr = 0; rr < 4; ++rr) {
                int r = orow0 + rr;
                if (r < N) {
                    float pre = acc[ct][rr] + bv[ct];
                    float o = fmaxf(pre * scv[ct] + shv[ct], 0.f);
                    uint32 xv = xh[(size_t)r * 64 + (ocol >> 1)];
                    float xr = (ocol & 1) ? h2hi(xv) : h2lo(xv);
                    out[(size_t)r * 128 + ocol] = o + xr;
                }
            }
        }
    }
}

// ---------------- launcher ----------------

extern "C" void kernel_launch(void* const* d_in, const int* in_sizes, int n_in,
                              void* d_out, int out_size, void* d_ws, size_t ws_size,
                              hipStream_t stream) {
    const float* x     = (const float*)d_in[0];
    const int*   ei    = (const int*)d_in[1];
    const float* W     = (const float*)d_in[2];
    const float* bias  = (const float*)d_in[3];
    const float* gamma = (const float*)d_in[4];
    const float* beta  = (const float*)d_in[5];
    float* out = (float*)d_out;

    const int D = 128;
    int N = in_sizes[0] / D;           // requires N <= 256*1024 (8-bit local, 1024 buckets)
    int E = in_sizes[1] / 2;
    int NB = (N + 255) >> 8;           // 256-node buckets

    const int GSTATS = 256;
    const int GAPPLY = 512;

    char* ws = (char*)d_ws;
    size_t off = 0;
    auto alloc = [&](size_t bytes) -> void* {
        void* p = ws + off;
        off += (bytes + 255) & ~(size_t)255;
        return p;
    };
    uint32* xh   = (uint32*)alloc((size_t)N * 64 * sizeof(uint32));   // x fp16
    uint32* aggh = (uint32*)alloc((size_t)N * 64 * sizeof(uint32));   // agg fp16
    uint32* bpack= (uint32*)alloc((size_t)E * sizeof(uint32));
    int* col     = (int*)alloc((size_t)E * sizeof(int));
    _Float16* Wh = (_Float16*)alloc((size_t)D * D * sizeof(_Float16));
    int* rowptr  = (int*)alloc((size_t)(N + 1) * sizeof(int));
    uint32* dpk  = (uint32*)alloc((size_t)N * sizeof(uint32));        // {dinv,dinv} fp16
    int* bbase   = (int*)alloc(1025 * sizeof(int));
    float* ss    = (float*)alloc(256 * sizeof(float));
    float* partials = (float*)alloc((size_t)GSTATS * 256 * sizeof(float));
    int* bcnt    = (int*)alloc(1024 * sizeof(int));   // zeroed
    int* bfill   = (int*)alloc(1024 * sizeof(int));   // zeroed (contiguous with bcnt)

    hipMemsetAsync(bcnt, 0, 2 * 1024 * sizeof(int), stream);

    k_prep<<<2048, 256, 0, stream>>>((const float4*)x, N * 32, (const float4*)W, D * D / 4,
                                     ei + E, E, NB, (uint2*)xh, (uint2*)Wh, bcnt);
    k_scan1024<<<1, 1024, 0, stream>>>(bcnt, NB, bbase);
    k_bscatter<<<256, 256, 0, stream>>>(ei, E, NB, bbase, bfill, bpack);
    k_csr<<<NB, 256, 0, stream>>>(bpack, bbase, N, E, rowptr, dpk, col);
    k_agg<<<(N + 3) / 4, 256, 0, stream>>>(xh, rowptr, col, dpk, aggh, N);

    int ntiles = (N + 63) / 64;
    k_gemm_stats<<<GSTATS, 256, 0, stream>>>((const _Float16*)aggh, Wh, bias, N, ntiles, partials);
    k_bnparams<<<1, 256, 0, stream>>>(partials, GSTATS, gamma, beta, 1.0f / (float)N, ss);
    k_gemm_apply<<<GAPPLY, 256, 0, stream>>>((const _Float16*)aggh, Wh, bias, ss, xh, N, ntiles, out);
}

// Round 6
// 193.101 us; speedup vs baseline: 2.6801x; 1.2576x over previous
//
#include <hip/hip_runtime.h>
#include <hip/hip_fp16.h>

#define BN_EPS 1e-5f

typedef unsigned int uint32;
typedef __attribute__((ext_vector_type(8))) _Float16 f16x8;
typedef __attribute__((ext_vector_type(4))) float f32x4;

union H2U { __half2 h; uint32 u; };

__device__ __forceinline__ __half2 u2h(uint32 u) { H2U c; c.u = u; return c.h; }
__device__ __forceinline__ uint32 h2u(__half2 h) { H2U c; c.h = h; return c.u; }
__device__ __forceinline__ uint32 pack2h(float a, float b) {
    return h2u(__halves2half2(__float2half_rn(a), __float2half_rn(b)));
}
__device__ __forceinline__ float h2lo(uint32 u) {
    return __half2float(__ushort_as_half((unsigned short)(u & 0xffffu)));
}
__device__ __forceinline__ float h2hi(uint32 u) {
    return __half2float(__ushort_as_half((unsigned short)(u >> 16)));
}

// ---------------- prep: convert x,W to fp16 + bucket histogram of dst ----------------

__global__ void __launch_bounds__(256) k_prep(const float4* __restrict__ x4, int nx4,
                                              const float4* __restrict__ w4, int nw4,
                                              const int* __restrict__ dst, int E, int NB,
                                              uint2* __restrict__ xh4, uint2* __restrict__ wh4,
                                              int* __restrict__ bcnt) {
    __shared__ int h[1024];
    int t = threadIdx.x;
    if (blockIdx.x < 256) {  // bucket histogram over an E-slice
        for (int i = t; i < NB; i += 256) h[i] = 0;
        __syncthreads();
        int c0 = (int)((long long)blockIdx.x * E / 256);
        int c1 = (int)((long long)(blockIdx.x + 1) * E / 256);
        for (int e = c0 + t; e < c1; e += 256) atomicAdd(&h[dst[e] >> 8], 1);
        __syncthreads();
        for (int i = t; i < NB; i += 256)
            if (h[i]) atomicAdd(&bcnt[i], h[i]);
    }
    int idx = blockIdx.x * 256 + t;
    int stride = gridDim.x * 256;
    for (int i = idx; i < nx4; i += stride) {
        float4 v = x4[i];
        xh4[i] = make_uint2(pack2h(v.x, v.y), pack2h(v.z, v.w));
    }
    for (int i = idx; i < nw4; i += stride) {
        float4 v = w4[i];
        wh4[i] = make_uint2(pack2h(v.x, v.y), pack2h(v.z, v.w));
    }
}

// ---------------- exclusive scan of bucket counts (1 block) ----------------

__global__ void k_scan1024(const int* __restrict__ in, int n, int* __restrict__ outExcl) {
    __shared__ int s[1024];
    int t = threadIdx.x;
    int v = (t < n) ? in[t] : 0;
    s[t] = v;
    __syncthreads();
    for (int off = 1; off < 1024; off <<= 1) {
        int add = (t >= off) ? s[t - off] : 0;
        __syncthreads();
        s[t] += add;
        __syncthreads();
    }
    if (t < n) outExcl[t] = s[t] - v;
    if (t == n - 1) outExcl[n] = s[t];  // total = E
}

// ---------------- bucket scatter: bpack[pos] = (localDst<<24) | src ----------------

__global__ void __launch_bounds__(256) k_bscatter(const int* __restrict__ ei, int E, int NB,
                                                  const int* __restrict__ bbase,
                                                  int* __restrict__ bfill,
                                                  uint32* __restrict__ bpack) {
    __shared__ int h[1024];
    int t = threadIdx.x;
    int c0 = (int)((long long)blockIdx.x * E / gridDim.x);
    int c1 = (int)((long long)(blockIdx.x + 1) * E / gridDim.x);
    for (int i = t; i < NB; i += 256) h[i] = 0;
    __syncthreads();
    for (int e = c0 + t; e < c1; e += 256)
        atomicAdd(&h[ei[E + e] >> 8], 1);
    __syncthreads();
    for (int i = t; i < NB; i += 256) {
        int c = h[i];
        if (c > 0) h[i] = bbase[i] + atomicAdd(&bfill[i], c);
    }
    __syncthreads();
    for (int e = c0 + t; e < c1; e += 256) {
        int s = ei[e];
        int d = ei[E + e];
        int b = d >> 8;
        int pos = atomicAdd(&h[b], 1);
        bpack[pos] = ((uint32)(d & 255) << 24) | (uint32)s;
    }
}

// ---------------- per-bucket CSR: count, scan, rowptr, dinv(fp16x2), col ----------------

__global__ void __launch_bounds__(256) k_csr(const uint32* __restrict__ bpack,
                                             const int* __restrict__ bbase,
                                             int N, int E,
                                             int* __restrict__ rowptr,
                                             uint32* __restrict__ dpk,
                                             int* __restrict__ col) {
    __shared__ int h[256], s[256], cur[256];
    int b = blockIdx.x;
    int t = threadIdx.x;
    int e0 = bbase[b], e1 = bbase[b + 1];
    h[t] = 0;
    __syncthreads();
    for (int e = e0 + t; e < e1; e += 256)
        atomicAdd(&h[bpack[e] >> 24], 1);
    __syncthreads();
    int cnt = h[t];
    s[t] = cnt;
    __syncthreads();
    for (int off = 1; off < 256; off <<= 1) {
        int add = (t >= off) ? s[t - off] : 0;
        __syncthreads();
        s[t] += add;
        __syncthreads();
    }
    int excl = s[t] - cnt;
    int node = (b << 8) + t;
    if (node < N) {
        rowptr[node] = e0 + excl;
        float dv = rsqrtf((float)(cnt + 1));
        dpk[node] = pack2h(dv, dv);
        if (node == N - 1) rowptr[N] = E;
    }
    cur[t] = e0 + excl;
    __syncthreads();
    for (int e = e0 + t; e < e1; e += 256) {
        uint32 p = bpack[e];
        int pos = atomicAdd(&cur[p >> 24], 1);
        col[pos] = (int)(p & 0xffffffu);
    }
}

// ---------------- aggregation: wave-per-node, coalesced index load + shfl broadcast ------
// aggx[i] = di*(di*x[i] + sum_j dinv[j]*x[j])

__global__ void __launch_bounds__(256) k_agg(const uint32* __restrict__ xh,
                                             const int* __restrict__ rowptr,
                                             const int* __restrict__ col,
                                             const uint32* __restrict__ dpk,
                                             uint32* __restrict__ aggh, int N) {
    int wid = blockIdx.x * 4 + (threadIdx.x >> 6);
    if (wid >= N) return;
    int lane = threadIdx.x & 63;
    int g = lane >> 4, c = lane & 15;

    __half2 z = __float2half2_rn(0.f);
    __half2 acc0 = z, acc1 = z, acc2 = z, acc3 = z;

    int e0 = rowptr[wid], e1 = rowptr[wid + 1];
    for (int cb = e0; cb < e1; cb += 64) {
        int rem = e1 - cb;                          // > 0
        int lim = rem < 64 ? rem : 64;
        // one coalesced load of up to 64 edge indices, one gather of 64 weights
        int sL = (lane < lim) ? col[cb + lane] : 0;
        uint32 wL = (lane < lim) ? dpk[sL] : 0;
        for (int j0 = 0; j0 < lim; j0 += 4) {
            int j = j0 + g;                          // j <= 63
            int sj = __shfl(sL, j);
            uint32 wj = (uint32)__shfl((int)wL, j);  // 0 when j >= lim (wL masked)
            uint4 v = *(const uint4*)&xh[(size_t)sj * 64 + c * 4];
            acc0 = __hfma2(u2h(v.x), u2h(wj), acc0);
            acc1 = __hfma2(u2h(v.y), u2h(wj), acc1);
            acc2 = __hfma2(u2h(v.z), u2h(wj), acc2);
            acc3 = __hfma2(u2h(v.w), u2h(wj), acc3);
        }
    }
    // reduce across the 4 edge-groups (lanes xor 16, 32)
    uint32 u;
    u = __shfl_xor(h2u(acc0), 16); acc0 = __hadd2(acc0, u2h(u));
    u = __shfl_xor(h2u(acc0), 32); acc0 = __hadd2(acc0, u2h(u));
    u = __shfl_xor(h2u(acc1), 16); acc1 = __hadd2(acc1, u2h(u));
    u = __shfl_xor(h2u(acc1), 32); acc1 = __hadd2(acc1, u2h(u));
    u = __shfl_xor(h2u(acc2), 16); acc2 = __hadd2(acc2, u2h(u));
    u = __shfl_xor(h2u(acc2), 32); acc2 = __hadd2(acc2, u2h(u));
    u = __shfl_xor(h2u(acc3), 16); acc3 = __hadd2(acc3, u2h(u));
    u = __shfl_xor(h2u(acc3), 32); acc3 = __hadd2(acc3, u2h(u));

    if (g == 0) {
        float di = h2lo(dpk[wid]);
        uint4 sv = *(const uint4*)&xh[(size_t)wid * 64 + c * 4];
        uint4 o;
        o.x = pack2h(di * (di * h2lo(sv.x) + __low2float(acc0)),
                     di * (di * h2hi(sv.x) + __high2float(acc0)));
        o.y = pack2h(di * (di * h2lo(sv.y) + __low2float(acc1)),
                     di * (di * h2hi(sv.y) + __high2float(acc1)));
        o.z = pack2h(di * (di * h2lo(sv.z) + __low2float(acc2)),
                     di * (di * h2hi(sv.z) + __high2float(acc2)));
        o.w = pack2h(di * (di * h2lo(sv.w) + __low2float(acc3)),
                     di * (di * h2hi(sv.w) + __high2float(acc3)));
        *(uint4*)&aggh[(size_t)wid * 64 + c * 4] = o;
    }
}

// ---------------- persistent MFMA GEMM (fp16), W staged in LDS (XOR-swizzled) ----------

#define STAGE_W()                                                            \
    for (int m = threadIdx.x; m < 2048; m += 256) {                          \
        int row = m >> 4, cc = m & 15;                                       \
        uint4 v = *(const uint4*)&Wh[row * 128 + cc * 8];                    \
        *(uint4*)((char*)wlds + row * 256 + ((cc * 16) ^ ((row & 7) << 4))) = v; \
    }

#define MFMA_TILE(acc, tile)                                                 \
    {                                                                        \
        int arow = (tile) * 64 + wave * 16 + lrow;                           \
        bool avalid = arow < N;                                              \
        _Pragma("unroll")                                                    \
        for (int kc = 0; kc < 4; ++kc) {                                     \
            f16x8 a;                                                         \
            if (avalid) a = *(const f16x8*)&Ah[(size_t)arow * 128 + kc * 32 + g * 8]; \
            else        a = (f16x8){0, 0, 0, 0, 0, 0, 0, 0};                 \
            _Pragma("unroll")                                                \
            for (int ct = 0; ct < 8; ++ct) {                                 \
                int row = ct * 16 + lrow;                                    \
                const f16x8 bfr = *(const f16x8*)((const char*)wlds + row * 256 \
                                   + ((kc * 64 + g * 16) ^ ((row & 7) << 4))); \
                acc[ct] = __builtin_amdgcn_mfma_f32_16x16x32_f16(a, bfr, acc[ct], 0, 0, 0); \
            }                                                                \
        }                                                                    \
    }

__global__ void __launch_bounds__(256) k_gemm_stats(const _Float16* __restrict__ Ah,
                                                    const _Float16* __restrict__ Wh,
                                                    const float* __restrict__ bias,
                                                    int N, int ntiles,
                                                    float* __restrict__ partials) {
    __shared__ uint32 wlds[8192];
    __shared__ float red[1024];
    STAGE_W();
    __syncthreads();

    int t = threadIdx.x;
    int wave = t >> 6, lane = t & 63;
    int lrow = lane & 15, g = lane >> 4;

    float bv[8];
    #pragma unroll
    for (int ct = 0; ct < 8; ++ct) bv[ct] = bias[ct * 16 + lrow];

    float s[8], sq[8];
    #pragma unroll
    for (int ct = 0; ct < 8; ++ct) { s[ct] = 0.f; sq[ct] = 0.f; }

    for (int tile = blockIdx.x; tile < ntiles; tile += gridDim.x) {
        f32x4 acc[8];
        #pragma unroll
        for (int ct = 0; ct < 8; ++ct) acc[ct] = (f32x4){0.f, 0.f, 0.f, 0.f};
        MFMA_TILE(acc, tile);
        int orow0 = tile * 64 + wave * 16 + g * 4;
        #pragma unroll
        for (int ct = 0; ct < 8; ++ct) {
            #pragma unroll
            for (int rr = 0; rr < 4; ++rr) {
                if (orow0 + rr < N) {
                    float o = acc[ct][rr] + bv[ct];
                    s[ct] += o; sq[ct] += o * o;
                }
            }
        }
    }
    #pragma unroll
    for (int ct = 0; ct < 8; ++ct) {
        s[ct] += __shfl_xor(s[ct], 16); sq[ct] += __shfl_xor(sq[ct], 16);
        s[ct] += __shfl_xor(s[ct], 32); sq[ct] += __shfl_xor(sq[ct], 32);
    }
    if (lane < 16) {
        #pragma unroll
        for (int ct = 0; ct < 8; ++ct) {
            int colI = ct * 16 + lrow;
            red[wave * 256 + colI] = s[ct];
            red[wave * 256 + 128 + colI] = sq[ct];
        }
    }
    __syncthreads();
    if (t < 256)
        partials[blockIdx.x * 256 + t] = red[t] + red[256 + t] + red[512 + t] + red[768 + t];
}

// ---------------- BN params: parallel reduction of 256x256 partials ----------------

__global__ void __launch_bounds__(1024) k_bnparams(const float* __restrict__ partials, int nblk,
                                                   const float* __restrict__ gamma,
                                                   const float* __restrict__ beta,
                                                   float invN, float* __restrict__ ss) {
    __shared__ float red[1024];
    int tid = threadIdx.x;
    int colI = tid & 255, q = tid >> 8;          // 4 quarters of the blocks
    int bq = nblk >> 2;                           // nblk assumed multiple of 4
    float v0 = 0.f, v1 = 0.f, v2 = 0.f, v3 = 0.f;
    int b0 = q * bq;
    for (int b = b0; b < b0 + bq; b += 4) {
        v0 += partials[(b + 0) * 256 + colI];
        v1 += partials[(b + 1) * 256 + colI];
        v2 += partials[(b + 2) * 256 + colI];
        v3 += partials[(b + 3) * 256 + colI];
    }
    red[q * 256 + colI] = (v0 + v1) + (v2 + v3);
    __syncthreads();
    if (tid < 256) {
        float tot = red[tid] + red[256 + tid] + red[512 + tid] + red[768 + tid];
        red[tid] = tot;
    }
    __syncthreads();
    if (tid < 128) {
        float mean = red[tid] * invN;
        float var = red[128 + tid] * invN - mean * mean;
        float sc = gamma[tid] * rsqrtf(var + BN_EPS);
        ss[tid] = sc;
        ss[128 + tid] = beta[tid] - mean * sc;
    }
}

__global__ void __launch_bounds__(256) k_gemm_apply(const _Float16* __restrict__ Ah,
                                                    const _Float16* __restrict__ Wh,
                                                    const float* __restrict__ bias,
                                                    const float* __restrict__ ss,
                                                    const uint32* __restrict__ xh,
                                                    int N, int ntiles,
                                                    float* __restrict__ out) {
    __shared__ uint32 wlds[8192];
    STAGE_W();
    __syncthreads();

    int t = threadIdx.x;
    int wave = t >> 6, lane = t & 63;
    int lrow = lane & 15, g = lane >> 4;

    float bv[8], scv[8], shv[8];
    #pragma unroll
    for (int ct = 0; ct < 8; ++ct) {
        int colI = ct * 16 + lrow;
        bv[ct] = bias[colI]; scv[ct] = ss[colI]; shv[ct] = ss[128 + colI];
    }

    for (int tile = blockIdx.x; tile < ntiles; tile += gridDim.x) {
        f32x4 acc[8];
        #pragma unroll
        for (int ct = 0; ct < 8; ++ct) acc[ct] = (f32x4){0.f, 0.f, 0.f, 0.f};
        MFMA_TILE(acc, tile);
        int orow0 = tile * 64 + wave * 16 + g * 4;
        #pragma unroll
        for (int ct = 0; ct < 8; ++ct) {
            int ocol = ct * 16 + lrow;
            #pragma unroll
            for (int rr = 0; rr < 4; ++rr) {
                int r = orow0 + rr;
                if (r < N) {
                    float pre = acc[ct][rr] + bv[ct];
                    float o = fmaxf(pre * scv[ct] + shv[ct], 0.f);
                    uint32 xv = xh[(size_t)r * 64 + (ocol >> 1)];
                    float xr = (ocol & 1) ? h2hi(xv) : h2lo(xv);
                    out[(size_t)r * 128 + ocol] = o + xr;
                }
            }
        }
    }
}

// ---------------- launcher ----------------

extern "C" void kernel_launch(void* const* d_in, const int* in_sizes, int n_in,
                              void* d_out, int out_size, void* d_ws, size_t ws_size,
                              hipStream_t stream) {
    const float* x     = (const float*)d_in[0];
    const int*   ei    = (const int*)d_in[1];
    const float* W     = (const float*)d_in[2];
    const float* bias  = (const float*)d_in[3];
    const float* gamma = (const float*)d_in[4];
    const float* beta  = (const float*)d_in[5];
    float* out = (float*)d_out;

    const int D = 128;
    int N = in_sizes[0] / D;           // requires N <= 256*1024 (8-bit local, 1024 buckets)
    int E = in_sizes[1] / 2;
    int NB = (N + 255) >> 8;           // 256-node buckets

    const int GSTATS = 256;
    const int GAPPLY = 512;

    char* ws = (char*)d_ws;
    size_t off = 0;
    auto alloc = [&](size_t bytes) -> void* {
        void* p = ws + off;
        off += (bytes + 255) & ~(size_t)255;
        return p;
    };
    uint32* xh   = (uint32*)alloc((size_t)N * 64 * sizeof(uint32));   // x fp16
    uint32* aggh = (uint32*)alloc((size_t)N * 64 * sizeof(uint32));   // agg fp16
    uint32* bpack= (uint32*)alloc((size_t)E * sizeof(uint32));
    int* col     = (int*)alloc((size_t)E * sizeof(int));
    _Float16* Wh = (_Float16*)alloc((size_t)D * D * sizeof(_Float16));
    int* rowptr  = (int*)alloc((size_t)(N + 1) * sizeof(int));
    uint32* dpk  = (uint32*)alloc((size_t)N * sizeof(uint32));        // {dinv,dinv} fp16
    int* bbase   = (int*)alloc(1025 * sizeof(int));
    float* ss    = (float*)alloc(256 * sizeof(float));
    float* partials = (float*)alloc((size_t)GSTATS * 256 * sizeof(float));
    int* bcnt    = (int*)alloc(1024 * sizeof(int));   // zeroed
    int* bfill   = (int*)alloc(1024 * sizeof(int));   // zeroed (contiguous with bcnt)

    hipMemsetAsync(bcnt, 0, 2 * 1024 * sizeof(int), stream);

    k_prep<<<2048, 256, 0, stream>>>((const float4*)x, N * 32, (const float4*)W, D * D / 4,
                                     ei + E, E, NB, (uint2*)xh, (uint2*)Wh, bcnt);
    k_scan1024<<<1, 1024, 0, stream>>>(bcnt, NB, bbase);
    k_bscatter<<<256, 256, 0, stream>>>(ei, E, NB, bbase, bfill, bpack);
    k_csr<<<NB, 256, 0, stream>>>(bpack, bbase, N, E, rowptr, dpk, col);
    k_agg<<<(N + 3) / 4, 256, 0, stream>>>(xh, rowptr, col, dpk, aggh, N);

    int ntiles = (N + 63) / 64;
    k_gemm_stats<<<GSTATS, 256, 0, stream>>>((const _Float16*)aggh, Wh, bias, N, ntiles, partials);
    k_bnparams<<<1, 1024, 0, stream>>>(partials, GSTATS, gamma, beta, 1.0f / (float)N, ss);
    k_gemm_apply<<<GAPPLY, 256, 0, stream>>>((const _Float16*)aggh, Wh, bias, ss, xh, N, ntiles, out);
}